// Round 1
// baseline (3919.427 us; speedup 1.0000x reference)
//
#include <hip/hip_runtime.h>

typedef short bf16x8 __attribute__((ext_vector_type(8)));
typedef float f32x4 __attribute__((ext_vector_type(4)));
typedef unsigned short u16;
typedef unsigned int u32;

#define NN 100000
#define NE 600000

__device__ __forceinline__ u16 f2b(float f) {
    u32 u = __float_as_uint(f);
    return (u16)((u + 0x7FFFu + ((u >> 16) & 1u)) >> 16);
}
__device__ __forceinline__ float b2f(u16 h) { return __uint_as_float(((u32)h) << 16); }

// ---------------- weight prep: transpose + bf16, combined sums ----------------
// Layout in wts (u16 elements):
//   0      Wsum0T [128][128]   (Ws0_r0+Ws0_r1)^T
//   16384  Wn0r0T [128][128]
//   32768  Wn0r1T [128][128]
//   49152  Wp0T   [128][128]
//   65536  Wp1T   [128][128]
//   81920  Wsum1T [64][128]    (Ws1_r0+Ws1_r1)^T
//   90112  Wn1r0T [64][128]
//   98304  Wn1r1T [64][128]
__global__ void prep_weights(
    const float* __restrict__ Ws0_0, const float* __restrict__ Ws0_1,
    const float* __restrict__ Wn0_0, const float* __restrict__ Wn0_1,
    const float* __restrict__ Wp_0,  const float* __restrict__ Wp_1,
    const float* __restrict__ Ws1_0, const float* __restrict__ Ws1_1,
    const float* __restrict__ Wn1_0, const float* __restrict__ Wn1_1,
    const float* __restrict__ b0_0, const float* __restrict__ b0_1,
    const float* __restrict__ b1_0, const float* __restrict__ b1_1,
    u16* __restrict__ w, float* __restrict__ bsum0, float* __restrict__ bsum1)
{
    int t = blockIdx.x * 256 + threadIdx.x;
    if (t < 81920) {                      // five 128x128 transposes
        int m = t >> 14, u = t & 16383;
        int n = u >> 7, k = u & 127;      // out[n][k] = in[k][n]
        float v;
        if (m == 0)      v = Ws0_0[k * 128 + n] + Ws0_1[k * 128 + n];
        else if (m == 1) v = Wn0_0[k * 128 + n];
        else if (m == 2) v = Wn0_1[k * 128 + n];
        else if (m == 3) v = Wp_0[k * 128 + n];
        else             v = Wp_1[k * 128 + n];
        w[t] = f2b(v);
    } else if (t < 106496) {              // three 128x64 transposes
        int u = t - 81920;
        int m = u >> 13; u &= 8191;
        int n = u >> 7, k = u & 127;
        float v;
        if (m == 0)      v = Ws1_0[k * 64 + n] + Ws1_1[k * 64 + n];
        else if (m == 1) v = Wn1_0[k * 64 + n];
        else             v = Wn1_1[k * 64 + n];
        w[t] = f2b(v);
    } else if (t < 106624) {
        int i = t - 106496; bsum0[i] = b0_0[i] + b0_1[i];
    } else if (t < 106688) {
        int i = t - 106624; bsum1[i] = b1_0[i] + b1_1[i];
    }
}

// ---------------- x -> bf16 ----------------
__global__ void conv_x(const float* __restrict__ x, u16* __restrict__ o) {
    int t = blockIdx.x * 256 + threadIdx.x;           // exactly NN*128/4 threads
    const float4 v = reinterpret_cast<const float4*>(x)[t];
    ushort4 r; r.x = f2b(v.x); r.y = f2b(v.y); r.z = f2b(v.z); r.w = f2b(v.w);
    reinterpret_cast<ushort4*>(o)[t] = r;
}

// ---------------- in-degree counts for both relations ----------------
__global__ void deg_count(const int* __restrict__ d0, const int* __restrict__ d1,
                          int* __restrict__ g0, int* __restrict__ g1) {
    int e = blockIdx.x * 256 + threadIdx.x;
    if (e < NE) { atomicAdd(&g0[d0[e]], 1); atomicAdd(&g1[d1[e]], 1); }
}

// ---------------- mean aggregation: scatter-add ----------------
__global__ void scatter_mean(const float* __restrict__ x, const int* __restrict__ src,
                             const int* __restrict__ dst, const float* __restrict__ ew,
                             float* __restrict__ s)
{
    int t = blockIdx.x * 256 + threadIdx.x;           // exactly NE*32 threads
    int e = t >> 5;
    int f = (t & 31) << 2;
    int si = src[e], di = dst[e];
    float wgt = ew[e];
    const float4 v = *reinterpret_cast<const float4*>(x + (size_t)si * 128 + f);
    float* o = s + (size_t)di * 128 + f;
    atomicAdd(o + 0, v.x * wgt);
    atomicAdd(o + 1, v.y * wgt);
    atomicAdd(o + 2, v.z * wgt);
    atomicAdd(o + 3, v.w * wgt);
}

__global__ void finalize_mean(const float* __restrict__ s, const int* __restrict__ deg,
                              u16* __restrict__ o)
{
    int t = blockIdx.x * 256 + threadIdx.x;           // exactly NN*32 threads
    int i = t >> 5, f = (t & 31) << 2;
    float inv = 1.f / fmaxf((float)deg[i], 1.f);
    const float4 v = *reinterpret_cast<const float4*>(s + (size_t)i * 128 + f);
    ushort4 r; r.x = f2b(v.x * inv); r.y = f2b(v.y * inv);
    r.z = f2b(v.z * inv); r.w = f2b(v.w * inv);
    *reinterpret_cast<ushort4*>(o + (size_t)i * 128 + f) = r;
}

// ---------------- max aggregation: scatter-max on u32 bits (all msgs >= 0) ----------------
__global__ void scatter_max(const u16* __restrict__ hp, const int* __restrict__ src,
                            const int* __restrict__ dst, const float* __restrict__ ew,
                            u32* __restrict__ s)
{
    int t = blockIdx.x * 256 + threadIdx.x;           // exactly NE*32 threads
    int e = t >> 5, f = (t & 31) << 2;
    int si = src[e], di = dst[e];
    float wgt = ew[e];
    const ushort4 hv = *reinterpret_cast<const ushort4*>(hp + (size_t)si * 128 + f);
    u32* o = s + (size_t)di * 128 + f;
    atomicMax(o + 0, __float_as_uint(b2f(hv.x) * wgt));
    atomicMax(o + 1, __float_as_uint(b2f(hv.y) * wgt));
    atomicMax(o + 2, __float_as_uint(b2f(hv.z) * wgt));
    atomicMax(o + 3, __float_as_uint(b2f(hv.w) * wgt));
}

__global__ void finalize_max(const u32* __restrict__ s, u16* __restrict__ o)
{
    int t = blockIdx.x * 256 + threadIdx.x;           // exactly NN*32 threads
    int i = t >> 5, f = (t & 31) << 2;
    const uint4 v = *reinterpret_cast<const uint4*>(s + (size_t)i * 128 + f);
    ushort4 r;
    r.x = f2b(__uint_as_float(v.x)); r.y = f2b(__uint_as_float(v.y));
    r.z = f2b(__uint_as_float(v.z)); r.w = f2b(__uint_as_float(v.w));
    *reinterpret_cast<ushort4*>(o + (size_t)i * 128 + f) = r;
}

// ---------------- fused multi-pair MFMA GEMM ----------------
// C[M x N] = act( sum_p A_p[M x 128] @ B_p[128 x N] + bias ), A bf16, B = W^T bf16 [N][128]
// Block: 128 rows, 4 waves x 32 rows. mfma_f32_16x16x32_bf16.
// A frag: lane l holds A[l&15][(l>>4)*8 + j]; B frag: B^T[col=l&15][k=(l>>4)*8+j];
// D frag: row=(l>>4)*4+reg, col=l&15  (m89-verified).
template<int NF, int NPAIR, bool RELU, bool OUTF32>
__global__ __launch_bounds__(256) void gemm_mfma(
    const u16* __restrict__ A0, const u16* __restrict__ A1, const u16* __restrict__ A2,
    const u16* __restrict__ B0, const u16* __restrict__ B1, const u16* __restrict__ B2,
    const float* __restrict__ bias, float* __restrict__ outF, u16* __restrict__ outB)
{
    constexpr int N = NF * 16;
    const int w = threadIdx.x >> 6;
    const int l = threadIdx.x & 63;
    const int l15 = l & 15;
    const int lk = (l >> 4) << 3;
    const int rowbase = blockIdx.x * 128 + w * 32;

    f32x4 acc[2][NF];
#pragma unroll
    for (int rf = 0; rf < 2; ++rf)
#pragma unroll
        for (int cf = 0; cf < NF; ++cf)
            acc[rf][cf] = f32x4{0.f, 0.f, 0.f, 0.f};

    const u16* As[3] = {A0, A1, A2};
    const u16* Bs[3] = {B0, B1, B2};

    int r0 = rowbase + l15;      if (r0 > NN - 1) r0 = NN - 1;
    int r1 = rowbase + 16 + l15; if (r1 > NN - 1) r1 = NN - 1;

#pragma unroll
    for (int p = 0; p < NPAIR; ++p) {
        const u16* A = As[p];
        const u16* B = Bs[p];
#pragma unroll
        for (int ks = 0; ks < 4; ++ks) {
            const int k0 = ks * 32 + lk;
            bf16x8 a0 = *reinterpret_cast<const bf16x8*>(A + (size_t)r0 * 128 + k0);
            bf16x8 a1 = *reinterpret_cast<const bf16x8*>(A + (size_t)r1 * 128 + k0);
#pragma unroll
            for (int cf = 0; cf < NF; ++cf) {
                bf16x8 b = *reinterpret_cast<const bf16x8*>(B + (cf * 16 + l15) * 128 + k0);
                acc[0][cf] = __builtin_amdgcn_mfma_f32_16x16x32_bf16(a0, b, acc[0][cf], 0, 0, 0);
                acc[1][cf] = __builtin_amdgcn_mfma_f32_16x16x32_bf16(a1, b, acc[1][cf], 0, 0, 0);
            }
        }
    }

    const int rq = (l >> 4) << 2;
#pragma unroll
    for (int cf = 0; cf < NF; ++cf) {
        const int col = cf * 16 + l15;
        const float bv = bias[col];
#pragma unroll
        for (int rf = 0; rf < 2; ++rf) {
#pragma unroll
            for (int j = 0; j < 4; ++j) {
                const int row = rowbase + rf * 16 + rq + j;
                if (row < NN) {
                    float v = acc[rf][cf][j] + bv;
                    if (RELU) v = fmaxf(v, 0.f);
                    if (OUTF32) outF[(size_t)row * N + col] = v;
                    else        outB[(size_t)row * N + col] = f2b(v);
                }
            }
        }
    }
}

extern "C" void kernel_launch(void* const* d_in, const int* in_sizes, int n_in,
                              void* d_out, int out_size, void* d_ws, size_t ws_size,
                              hipStream_t stream)
{
    const float* x     = (const float*)d_in[0];
    const int*   src0  = (const int*)d_in[1];
    const int*   dst0  = (const int*)d_in[2];
    const float* ew0   = (const float*)d_in[3];
    const int*   src1  = (const int*)d_in[4];
    const int*   dst1  = (const int*)d_in[5];
    const float* ew1   = (const float*)d_in[6];
    const float* Ws0_0 = (const float*)d_in[7];
    const float* Wn0_0 = (const float*)d_in[8];
    const float* b0_0  = (const float*)d_in[9];
    const float* Wp_0  = (const float*)d_in[10];
    const float* bp_0  = (const float*)d_in[11];
    const float* Ws1_0 = (const float*)d_in[12];
    const float* Wn1_0 = (const float*)d_in[13];
    const float* b1_0  = (const float*)d_in[14];
    const float* Ws0_1 = (const float*)d_in[15];
    const float* Wn0_1 = (const float*)d_in[16];
    const float* b0_1  = (const float*)d_in[17];
    const float* Wp_1  = (const float*)d_in[18];
    const float* bp_1  = (const float*)d_in[19];
    const float* Ws1_1 = (const float*)d_in[20];
    const float* Wn1_1 = (const float*)d_in[21];
    const float* b1_1  = (const float*)d_in[22];

    char* ws = (char*)d_ws;
    u16*   x16   = (u16*)(ws + 0);            // x bf16 (25.6MB); reused as hp later
    u16*   h16   = (u16*)(ws + 25600000);     // h bf16
    u16*   a0    = (u16*)(ws + 51200000);     // agg r0 bf16; reused as m0
    u16*   a1    = (u16*)(ws + 76800000);     // agg r1 bf16; reused as m1
    float* s     = (float*)(ws + 102400000);  // 51.2MB f32/u32 scatter accumulator
    int*   deg0  = (int*)(ws + 153600000);
    int*   deg1  = (int*)(ws + 154000000);
    u16*   wts   = (u16*)(ws + 154400000);
    float* bsum0 = (float*)(ws + 154612992);
    float* bsum1 = (float*)(ws + 154613504);

    const u16* Wsum0T = wts;
    const u16* Wn0r0T = wts + 16384;
    const u16* Wn0r1T = wts + 32768;
    const u16* Wp0T   = wts + 49152;
    const u16* Wp1T   = wts + 65536;
    const u16* Wsum1T = wts + 81920;
    const u16* Wn1r0T = wts + 90112;
    const u16* Wn1r1T = wts + 98304;

    prep_weights<<<417, 256, 0, stream>>>(Ws0_0, Ws0_1, Wn0_0, Wn0_1, Wp_0, Wp_1,
                                          Ws1_0, Ws1_1, Wn1_0, Wn1_1,
                                          b0_0, b0_1, b1_0, b1_1, wts, bsum0, bsum1);
    conv_x<<<12500, 256, 0, stream>>>(x, x16);

    hipMemsetAsync(deg0, 0, 400000, stream);
    hipMemsetAsync(deg1, 0, 400000, stream);
    deg_count<<<2344, 256, 0, stream>>>(dst0, dst1, deg0, deg1);

    // ---- layer 0: mean aggregation per relation ----
    hipMemsetAsync(s, 0, 51200000, stream);
    scatter_mean<<<75000, 256, 0, stream>>>(x, src0, dst0, ew0, s);
    finalize_mean<<<12500, 256, 0, stream>>>(s, deg0, a0);
    hipMemsetAsync(s, 0, 51200000, stream);
    scatter_mean<<<75000, 256, 0, stream>>>(x, src1, dst1, ew1, s);
    finalize_mean<<<12500, 256, 0, stream>>>(s, deg1, a1);

    // h = relu(x@Wsum0 + a0@Wn0_r0 + a1@Wn0_r1 + bsum0)
    gemm_mfma<8, 3, true, false><<<782, 256, 0, stream>>>(
        x16, a0, a1, Wsum0T, Wn0r0T, Wn0r1T, bsum0, nullptr, h16);

    // ---- layer 1, relation 0: hp = relu(h@Wp0 + bp0); m0 = maxagg ----
    gemm_mfma<8, 1, true, false><<<782, 256, 0, stream>>>(
        h16, nullptr, nullptr, Wp0T, nullptr, nullptr, bp_0, nullptr, x16);
    hipMemsetAsync(s, 0, 51200000, stream);
    scatter_max<<<75000, 256, 0, stream>>>(x16, src0, dst0, ew0, (u32*)s);
    finalize_max<<<12500, 256, 0, stream>>>((const u32*)s, a0);

    // ---- layer 1, relation 1 ----
    gemm_mfma<8, 1, true, false><<<782, 256, 0, stream>>>(
        h16, nullptr, nullptr, Wp1T, nullptr, nullptr, bp_1, nullptr, x16);
    hipMemsetAsync(s, 0, 51200000, stream);
    scatter_max<<<75000, 256, 0, stream>>>(x16, src1, dst1, ew1, (u32*)s);
    finalize_max<<<12500, 256, 0, stream>>>((const u32*)s, a1);

    // logits = h@Wsum1 + m0@Wn1_r0 + m1@Wn1_r1 + bsum1
    gemm_mfma<4, 3, false, true><<<782, 256, 0, stream>>>(
        h16, a0, a1, Wsum1T, Wn1r0T, Wn1r1T, bsum1, (float*)d_out, nullptr);
}

// Round 2
// 626.726 us; speedup vs baseline: 6.2538x; 6.2538x over previous
//
#include <hip/hip_runtime.h>

typedef short bf16x8 __attribute__((ext_vector_type(8)));
typedef float f32x4 __attribute__((ext_vector_type(4)));
typedef unsigned short u16;
typedef unsigned int u32;

#define NN 100000
#define NE 600000

__device__ __forceinline__ u16 f2b(float f) {
    u32 u = __float_as_uint(f);
    return (u16)((u + 0x7FFFu + ((u >> 16) & 1u)) >> 16);
}
__device__ __forceinline__ float b2f(u16 h) { return __uint_as_float(((u32)h) << 16); }

// ---------------- weight prep: transpose + bf16, combined sums ----------------
__global__ void prep_weights(
    const float* __restrict__ Ws0_0, const float* __restrict__ Ws0_1,
    const float* __restrict__ Wn0_0, const float* __restrict__ Wn0_1,
    const float* __restrict__ Wp_0,  const float* __restrict__ Wp_1,
    const float* __restrict__ Ws1_0, const float* __restrict__ Ws1_1,
    const float* __restrict__ Wn1_0, const float* __restrict__ Wn1_1,
    const float* __restrict__ b0_0, const float* __restrict__ b0_1,
    const float* __restrict__ b1_0, const float* __restrict__ b1_1,
    u16* __restrict__ w, float* __restrict__ bsum0, float* __restrict__ bsum1)
{
    int t = blockIdx.x * 256 + threadIdx.x;
    if (t < 81920) {                      // five 128x128 transposes
        int m = t >> 14, u = t & 16383;
        int n = u >> 7, k = u & 127;      // out[n][k] = in[k][n]
        float v;
        if (m == 0)      v = Ws0_0[k * 128 + n] + Ws0_1[k * 128 + n];
        else if (m == 1) v = Wn0_0[k * 128 + n];
        else if (m == 2) v = Wn0_1[k * 128 + n];
        else if (m == 3) v = Wp_0[k * 128 + n];
        else             v = Wp_1[k * 128 + n];
        w[t] = f2b(v);
    } else if (t < 106496) {              // three 128x64 transposes
        int u = t - 81920;
        int m = u >> 13; u &= 8191;
        int n = u >> 7, k = u & 127;
        float v;
        if (m == 0)      v = Ws1_0[k * 64 + n] + Ws1_1[k * 64 + n];
        else if (m == 1) v = Wn1_0[k * 64 + n];
        else             v = Wn1_1[k * 64 + n];
        w[t] = f2b(v);
    } else if (t < 106624) {
        int i = t - 106496; bsum0[i] = b0_0[i] + b0_1[i];
    } else if (t < 106688) {
        int i = t - 106624; bsum1[i] = b1_0[i] + b1_1[i];
    }
}

// ---------------- x -> bf16 ----------------
__global__ void conv_x(const float* __restrict__ x, u16* __restrict__ o) {
    int t = blockIdx.x * 256 + threadIdx.x;           // exactly NN*128/4 threads
    const float4 v = reinterpret_cast<const float4*>(x)[t];
    ushort4 r; r.x = f2b(v.x); r.y = f2b(v.y); r.z = f2b(v.z); r.w = f2b(v.w);
    reinterpret_cast<ushort4*>(o)[t] = r;
}

// ---------------- in-degree counts for both relations ----------------
__global__ void deg_count(const int* __restrict__ d0, const int* __restrict__ d1,
                          int* __restrict__ g0, int* __restrict__ g1) {
    int e = blockIdx.x * 256 + threadIdx.x;
    if (e < NE) { atomicAdd(&g0[d0[e]], 1); atomicAdd(&g1[d1[e]], 1); }
}

// ---------------- prefix scan (3 kernels) ----------------
__global__ void scan_local(const int* __restrict__ in, int* __restrict__ out,
                           int* __restrict__ bsum, int n)
{
    __shared__ int sm[1024];
    int t = threadIdx.x;
    int i = blockIdx.x * 1024 + t;
    int v = (i < n) ? in[i] : 0;
    sm[t] = v;
    __syncthreads();
    for (int off = 1; off < 1024; off <<= 1) {
        int add = (t >= off) ? sm[t - off] : 0;
        __syncthreads();
        sm[t] += add;
        __syncthreads();
    }
    if (i < n) out[i] = sm[t] - v;            // exclusive
    if (t == 1023) bsum[blockIdx.x] = sm[1023];
}

__global__ void scan_bsums(int* __restrict__ bsum, int nb)
{
    __shared__ int sm[128];
    int t = threadIdx.x;
    int v = (t < nb) ? bsum[t] : 0;
    sm[t] = v;
    __syncthreads();
    for (int off = 1; off < 128; off <<= 1) {
        int add = (t >= off) ? sm[t - off] : 0;
        __syncthreads();
        sm[t] += add;
        __syncthreads();
    }
    if (t < nb) bsum[t] = sm[t] - v;          // exclusive
}

__global__ void scan_add(int* __restrict__ offs, const int* __restrict__ bsum,
                         int* __restrict__ cur, int n, int total)
{
    int i = blockIdx.x * 256 + threadIdx.x;
    if (i < n) {
        int v = offs[i] + bsum[i >> 10];
        offs[i] = v;
        cur[i] = v;
    }
    if (i == 0) offs[n] = total;
}

// ---------------- CSR build: place each edge at its slot ----------------
__global__ void build_csr(const int* __restrict__ src, const int* __restrict__ dst,
                          const float* __restrict__ ew, int* __restrict__ cur,
                          int2* __restrict__ csr)
{
    int e = blockIdx.x * 256 + threadIdx.x;
    if (e < NE) {
        int d = dst[e];
        int p = atomicAdd(&cur[d], 1);
        csr[p] = make_int2(src[e], __float_as_int(ew[e]));
    }
}

// ---------------- gather mean: one wave per node, f32 x, 2 feats/lane ----------------
__global__ __launch_bounds__(256) void gather_mean(
    const float* __restrict__ x, const int* __restrict__ offs,
    const int2* __restrict__ csr, u16* __restrict__ out)
{
    int node = blockIdx.x * 4 + (threadIdx.x >> 6);
    if (node >= NN) return;
    int lane = threadIdx.x & 63;
    int beg = offs[node], end = offs[node + 1];
    float a0 = 0.f, a1 = 0.f;
    for (int e = beg; e < end; ++e) {
        int2 m = csr[e];
        float w = __int_as_float(m.y);
        const float2 v = *reinterpret_cast<const float2*>(x + (size_t)m.x * 128 + lane * 2);
        a0 += v.x * w;
        a1 += v.y * w;
    }
    float inv = 1.f / fmaxf((float)(end - beg), 1.f);
    ushort2 r; r.x = f2b(a0 * inv); r.y = f2b(a1 * inv);
    *reinterpret_cast<ushort2*>(out + (size_t)node * 128 + lane * 2) = r;
}

// ---------------- gather max: one wave per node, bf16 hp (msgs >= 0, 0-init ok) ----------------
__global__ __launch_bounds__(256) void gather_max(
    const u16* __restrict__ hp, const int* __restrict__ offs,
    const int2* __restrict__ csr, u16* __restrict__ out)
{
    int node = blockIdx.x * 4 + (threadIdx.x >> 6);
    if (node >= NN) return;
    int lane = threadIdx.x & 63;
    int beg = offs[node], end = offs[node + 1];
    float a0 = 0.f, a1 = 0.f;
    for (int e = beg; e < end; ++e) {
        int2 m = csr[e];
        float w = __int_as_float(m.y);
        const u32 v = *reinterpret_cast<const u32*>(hp + (size_t)m.x * 128 + lane * 2);
        a0 = fmaxf(a0, b2f((u16)(v & 0xFFFFu)) * w);
        a1 = fmaxf(a1, b2f((u16)(v >> 16)) * w);
    }
    ushort2 r; r.x = f2b(a0); r.y = f2b(a1);
    *reinterpret_cast<ushort2*>(out + (size_t)node * 128 + lane * 2) = r;
}

// ---------------- fused multi-pair MFMA GEMM ----------------
template<int NF, int NPAIR, bool RELU, bool OUTF32>
__global__ __launch_bounds__(256) void gemm_mfma(
    const u16* __restrict__ A0, const u16* __restrict__ A1, const u16* __restrict__ A2,
    const u16* __restrict__ B0, const u16* __restrict__ B1, const u16* __restrict__ B2,
    const float* __restrict__ bias, float* __restrict__ outF, u16* __restrict__ outB)
{
    constexpr int N = NF * 16;
    const int w = threadIdx.x >> 6;
    const int l = threadIdx.x & 63;
    const int l15 = l & 15;
    const int lk = (l >> 4) << 3;
    const int rowbase = blockIdx.x * 128 + w * 32;

    f32x4 acc[2][NF];
#pragma unroll
    for (int rf = 0; rf < 2; ++rf)
#pragma unroll
        for (int cf = 0; cf < NF; ++cf)
            acc[rf][cf] = f32x4{0.f, 0.f, 0.f, 0.f};

    const u16* As[3] = {A0, A1, A2};
    const u16* Bs[3] = {B0, B1, B2};

    int r0 = rowbase + l15;      if (r0 > NN - 1) r0 = NN - 1;
    int r1 = rowbase + 16 + l15; if (r1 > NN - 1) r1 = NN - 1;

#pragma unroll
    for (int p = 0; p < NPAIR; ++p) {
        const u16* A = As[p];
        const u16* B = Bs[p];
#pragma unroll
        for (int ks = 0; ks < 4; ++ks) {
            const int k0 = ks * 32 + lk;
            bf16x8 a0 = *reinterpret_cast<const bf16x8*>(A + (size_t)r0 * 128 + k0);
            bf16x8 a1 = *reinterpret_cast<const bf16x8*>(A + (size_t)r1 * 128 + k0);
#pragma unroll
            for (int cf = 0; cf < NF; ++cf) {
                bf16x8 b = *reinterpret_cast<const bf16x8*>(B + (cf * 16 + l15) * 128 + k0);
                acc[0][cf] = __builtin_amdgcn_mfma_f32_16x16x32_bf16(a0, b, acc[0][cf], 0, 0, 0);
                acc[1][cf] = __builtin_amdgcn_mfma_f32_16x16x32_bf16(a1, b, acc[1][cf], 0, 0, 0);
            }
        }
    }

    const int rq = (l >> 4) << 2;
#pragma unroll
    for (int cf = 0; cf < NF; ++cf) {
        const int col = cf * 16 + l15;
        const float bv = bias[col];
#pragma unroll
        for (int rf = 0; rf < 2; ++rf) {
#pragma unroll
            for (int j = 0; j < 4; ++j) {
                const int row = rowbase + rf * 16 + rq + j;
                if (row < NN) {
                    float v = acc[rf][cf][j] + bv;
                    if (RELU) v = fmaxf(v, 0.f);
                    if (OUTF32) outF[(size_t)row * N + col] = v;
                    else        outB[(size_t)row * N + col] = f2b(v);
                }
            }
        }
    }
}

extern "C" void kernel_launch(void* const* d_in, const int* in_sizes, int n_in,
                              void* d_out, int out_size, void* d_ws, size_t ws_size,
                              hipStream_t stream)
{
    const float* x     = (const float*)d_in[0];
    const int*   src0  = (const int*)d_in[1];
    const int*   dst0  = (const int*)d_in[2];
    const float* ew0   = (const float*)d_in[3];
    const int*   src1  = (const int*)d_in[4];
    const int*   dst1  = (const int*)d_in[5];
    const float* ew1   = (const float*)d_in[6];
    const float* Ws0_0 = (const float*)d_in[7];
    const float* Wn0_0 = (const float*)d_in[8];
    const float* b0_0  = (const float*)d_in[9];
    const float* Wp_0  = (const float*)d_in[10];
    const float* bp_0  = (const float*)d_in[11];
    const float* Ws1_0 = (const float*)d_in[12];
    const float* Wn1_0 = (const float*)d_in[13];
    const float* b1_0  = (const float*)d_in[14];
    const float* Ws0_1 = (const float*)d_in[15];
    const float* Wn0_1 = (const float*)d_in[16];
    const float* b0_1  = (const float*)d_in[17];
    const float* Wp_1  = (const float*)d_in[18];
    const float* bp_1  = (const float*)d_in[19];
    const float* Ws1_1 = (const float*)d_in[20];
    const float* Wn1_1 = (const float*)d_in[21];
    const float* b1_1  = (const float*)d_in[22];

    char* ws = (char*)d_ws;
    u16*   x16   = (u16*)(ws + 0);            // x bf16; reused as hp later
    u16*   h16   = (u16*)(ws + 25600000);
    u16*   a0    = (u16*)(ws + 51200000);     // agg r0 bf16; reused as m0
    u16*   a1    = (u16*)(ws + 76800000);     // agg r1 bf16; reused as m1
    int2*  csr0  = (int2*)(ws + 102400000);   // 4.8MB
    int2*  csr1  = (int2*)(ws + 107200000);   // 4.8MB
    int*   offs0 = (int*)(ws + 112000000);    // NN+1
    int*   offs1 = (int*)(ws + 112400016);
    int*   cur0  = (int*)(ws + 112800032);
    int*   cur1  = (int*)(ws + 113200032);
    int*   deg0  = (int*)(ws + 113600032);
    int*   deg1  = (int*)(ws + 114000032);
    int*   bsA   = (int*)(ws + 114400032);    // 98-entry block sums
    int*   bsB   = (int*)(ws + 114400544);
    u16*   wts   = (u16*)(ws + 114401056);
    float* bsum0 = (float*)(ws + 114615072);
    float* bsum1 = (float*)(ws + 114615584);

    const u16* Wsum0T = wts;
    const u16* Wn0r0T = wts + 16384;
    const u16* Wn0r1T = wts + 32768;
    const u16* Wp0T   = wts + 49152;
    const u16* Wp1T   = wts + 65536;
    const u16* Wsum1T = wts + 81920;
    const u16* Wn1r0T = wts + 90112;
    const u16* Wn1r1T = wts + 98304;

    prep_weights<<<417, 256, 0, stream>>>(Ws0_0, Ws0_1, Wn0_0, Wn0_1, Wp_0, Wp_1,
                                          Ws1_0, Ws1_1, Wn1_0, Wn1_1,
                                          b0_0, b0_1, b1_0, b1_1, wts, bsum0, bsum1);
    conv_x<<<12500, 256, 0, stream>>>(x, x16);

    // ---- CSR build for both relations ----
    hipMemsetAsync(deg0, 0, 400000, stream);
    hipMemsetAsync(deg1, 0, 400000, stream);
    deg_count<<<2344, 256, 0, stream>>>(dst0, dst1, deg0, deg1);

    scan_local<<<98, 1024, 0, stream>>>(deg0, offs0, bsA, NN);
    scan_local<<<98, 1024, 0, stream>>>(deg1, offs1, bsB, NN);
    scan_bsums<<<1, 128, 0, stream>>>(bsA, 98);
    scan_bsums<<<1, 128, 0, stream>>>(bsB, 98);
    scan_add<<<391, 256, 0, stream>>>(offs0, bsA, cur0, NN, NE);
    scan_add<<<391, 256, 0, stream>>>(offs1, bsB, cur1, NN, NE);

    build_csr<<<2344, 256, 0, stream>>>(src0, dst0, ew0, cur0, csr0);
    build_csr<<<2344, 256, 0, stream>>>(src1, dst1, ew1, cur1, csr1);

    // ---- layer 0: mean aggregation (gather, no atomics) ----
    gather_mean<<<25000, 256, 0, stream>>>(x, offs0, csr0, a0);
    gather_mean<<<25000, 256, 0, stream>>>(x, offs1, csr1, a1);

    // h = relu(x@Wsum0 + a0@Wn0_r0 + a1@Wn0_r1 + bsum0)
    gemm_mfma<8, 3, true, false><<<782, 256, 0, stream>>>(
        x16, a0, a1, Wsum0T, Wn0r0T, Wn0r1T, bsum0, nullptr, h16);

    // ---- layer 1, relation 0: hp = relu(h@Wp0 + bp0); m0 = maxagg ----
    gemm_mfma<8, 1, true, false><<<782, 256, 0, stream>>>(
        h16, nullptr, nullptr, Wp0T, nullptr, nullptr, bp_0, nullptr, x16);
    gather_max<<<25000, 256, 0, stream>>>(x16, offs0, csr0, a0);

    // ---- layer 1, relation 1 ----
    gemm_mfma<8, 1, true, false><<<782, 256, 0, stream>>>(
        h16, nullptr, nullptr, Wp1T, nullptr, nullptr, bp_1, nullptr, x16);
    gather_max<<<25000, 256, 0, stream>>>(x16, offs1, csr1, a1);

    // logits = h@Wsum1 + m0@Wn1_r0 + m1@Wn1_r1 + bsum1
    gemm_mfma<4, 3, false, true><<<782, 256, 0, stream>>>(
        h16, a0, a1, Wsum1T, Wn1r0T, Wn1r1T, bsum1, (float*)d_out, nullptr);
}

// Round 3
// 515.908 us; speedup vs baseline: 7.5971x; 1.2148x over previous
//
#include <hip/hip_runtime.h>

typedef short bf16x8 __attribute__((ext_vector_type(8)));
typedef float f32x4 __attribute__((ext_vector_type(4)));
typedef unsigned short u16;
typedef unsigned int u32;

#define NN 100000
#define NE 600000

__device__ __forceinline__ u16 f2b(float f) {
    u32 u = __float_as_uint(f);
    return (u16)((u + 0x7FFFu + ((u >> 16) & 1u)) >> 16);
}
__device__ __forceinline__ float b2f(u16 h) { return __uint_as_float(((u32)h) << 16); }

// ---------------- weight prep: transpose + bf16, combined sums ----------------
__global__ void prep_weights(
    const float* __restrict__ Ws0_0, const float* __restrict__ Ws0_1,
    const float* __restrict__ Wn0_0, const float* __restrict__ Wn0_1,
    const float* __restrict__ Wp_0,  const float* __restrict__ Wp_1,
    const float* __restrict__ Ws1_0, const float* __restrict__ Ws1_1,
    const float* __restrict__ Wn1_0, const float* __restrict__ Wn1_1,
    const float* __restrict__ b0_0, const float* __restrict__ b0_1,
    const float* __restrict__ b1_0, const float* __restrict__ b1_1,
    u16* __restrict__ w, float* __restrict__ bsum0, float* __restrict__ bsum1)
{
    int t = blockIdx.x * 256 + threadIdx.x;
    if (t < 81920) {                      // five 128x128 transposes
        int m = t >> 14, u = t & 16383;
        int n = u >> 7, k = u & 127;      // out[n][k] = in[k][n]
        float v;
        if (m == 0)      v = Ws0_0[k * 128 + n] + Ws0_1[k * 128 + n];
        else if (m == 1) v = Wn0_0[k * 128 + n];
        else if (m == 2) v = Wn0_1[k * 128 + n];
        else if (m == 3) v = Wp_0[k * 128 + n];
        else             v = Wp_1[k * 128 + n];
        w[t] = f2b(v);
    } else if (t < 106496) {              // three 64x128 transposed (from 128x64)
        int u = t - 81920;
        int m = u >> 13; u &= 8191;
        int n = u >> 7, k = u & 127;
        float v;
        if (m == 0)      v = Ws1_0[k * 64 + n] + Ws1_1[k * 64 + n];
        else if (m == 1) v = Wn1_0[k * 64 + n];
        else             v = Wn1_1[k * 64 + n];
        w[t] = f2b(v);
    } else if (t < 106624) {
        int i = t - 106496; bsum0[i] = b0_0[i] + b0_1[i];
    } else if (t < 106688) {
        int i = t - 106624; bsum1[i] = b1_0[i] + b1_1[i];
    }
}

// ---------------- x -> bf16 ----------------
__global__ void conv_x(const float* __restrict__ x, u16* __restrict__ o) {
    int t = blockIdx.x * 256 + threadIdx.x;           // exactly NN*128/4 threads
    const float4 v = reinterpret_cast<const float4*>(x)[t];
    ushort4 r; r.x = f2b(v.x); r.y = f2b(v.y); r.z = f2b(v.z); r.w = f2b(v.w);
    reinterpret_cast<ushort4*>(o)[t] = r;
}

// ---------------- in-degree counts for both relations ----------------
__global__ void deg_count(const int* __restrict__ d0, const int* __restrict__ d1,
                          int* __restrict__ g0, int* __restrict__ g1) {
    int e = blockIdx.x * 256 + threadIdx.x;
    if (e < NE) { atomicAdd(&g0[d0[e]], 1); atomicAdd(&g1[d1[e]], 1); }
}

// ---------------- prefix scan (both relations in one dispatch) ----------------
__global__ void scan_local(const int* __restrict__ deg0, const int* __restrict__ deg1,
                           int* __restrict__ offs0, int* __restrict__ offs1,
                           int* __restrict__ bsA, int* __restrict__ bsB)
{
    __shared__ int sm[1024];
    int rel = blockIdx.x >= 98;
    int blk = blockIdx.x - rel * 98;
    const int* in = rel ? deg1 : deg0;
    int* out = rel ? offs1 : offs0;
    int* bsum = rel ? bsB : bsA;
    int t = threadIdx.x;
    int i = blk * 1024 + t;
    int v = (i < NN) ? in[i] : 0;
    sm[t] = v;
    __syncthreads();
    for (int off = 1; off < 1024; off <<= 1) {
        int add = (t >= off) ? sm[t - off] : 0;
        __syncthreads();
        sm[t] += add;
        __syncthreads();
    }
    if (i < NN) out[i] = sm[t] - v;            // exclusive
    if (t == 1023) bsum[blk] = sm[1023];
}

__global__ void scan_bsums(int* __restrict__ bsA, int* __restrict__ bsB)
{
    __shared__ int sm[128];
    int* bsum = blockIdx.x ? bsB : bsA;
    int t = threadIdx.x;
    int v = (t < 98) ? bsum[t] : 0;
    sm[t] = v;
    __syncthreads();
    for (int off = 1; off < 128; off <<= 1) {
        int add = (t >= off) ? sm[t - off] : 0;
        __syncthreads();
        sm[t] += add;
        __syncthreads();
    }
    if (t < 98) bsum[t] = sm[t] - v;           // exclusive
}

__global__ void scan_add(int* __restrict__ offs0, int* __restrict__ offs1,
                         const int* __restrict__ bsA, const int* __restrict__ bsB,
                         int* __restrict__ cur0, int* __restrict__ cur1)
{
    int rel = blockIdx.x >= 392;
    int i = (blockIdx.x - rel * 392) * 256 + threadIdx.x;
    int* offs = rel ? offs1 : offs0;
    int* cur = rel ? cur1 : cur0;
    const int* bsum = rel ? bsB : bsA;
    if (i < NN) {
        int v = offs[i] + bsum[i >> 10];
        offs[i] = v;
        cur[i] = v;
    }
    if (i == 0) offs[NN] = NE;
}

// ---------------- CSR build (both relations) ----------------
__global__ void build_csr(const int* __restrict__ src0, const int* __restrict__ dst0,
                          const float* __restrict__ ew0,
                          const int* __restrict__ src1, const int* __restrict__ dst1,
                          const float* __restrict__ ew1,
                          int* __restrict__ cur0, int* __restrict__ cur1,
                          int2* __restrict__ csr0, int2* __restrict__ csr1)
{
    int t = blockIdx.x * 256 + threadIdx.x;
    if (t < NE) {
        int p = atomicAdd(&cur0[dst0[t]], 1);
        csr0[p] = make_int2(src0[t], __float_as_int(ew0[t]));
    } else if (t < 2 * NE) {
        int e = t - NE;
        int p = atomicAdd(&cur1[dst1[e]], 1);
        csr1[p] = make_int2(src1[e], __float_as_int(ew1[e]));
    }
}

// ---------------- gather mean (bf16 input, both relations, unroll-2) ----------------
__global__ __launch_bounds__(256) void gather_mean(
    const u16* __restrict__ x16,
    const int* __restrict__ offs0, const int2* __restrict__ csr0, u16* __restrict__ o0,
    const int* __restrict__ offs1, const int2* __restrict__ csr1, u16* __restrict__ o1)
{
    int b = blockIdx.x;
    int rel = b >= 25000;
    const int* offs = rel ? offs1 : offs0;
    const int2* csr = rel ? csr1 : csr0;
    u16* out = rel ? o1 : o0;
    int node = (b - rel * 25000) * 4 + (threadIdx.x >> 6);
    int lane = threadIdx.x & 63;
    int beg = offs[node], end = offs[node + 1];
    float a0 = 0.f, a1 = 0.f, c0 = 0.f, c1 = 0.f;
    int e = beg;
    for (; e + 2 <= end; e += 2) {
        int2 m0 = csr[e], m1 = csr[e + 1];
        u32 v0 = *reinterpret_cast<const u32*>(x16 + (size_t)m0.x * 128 + lane * 2);
        u32 v1 = *reinterpret_cast<const u32*>(x16 + (size_t)m1.x * 128 + lane * 2);
        float w0 = __int_as_float(m0.y), w1 = __int_as_float(m1.y);
        a0 += b2f((u16)(v0 & 0xFFFFu)) * w0; a1 += b2f((u16)(v0 >> 16)) * w0;
        c0 += b2f((u16)(v1 & 0xFFFFu)) * w1; c1 += b2f((u16)(v1 >> 16)) * w1;
    }
    if (e < end) {
        int2 m0 = csr[e];
        u32 v0 = *reinterpret_cast<const u32*>(x16 + (size_t)m0.x * 128 + lane * 2);
        float w0 = __int_as_float(m0.y);
        a0 += b2f((u16)(v0 & 0xFFFFu)) * w0; a1 += b2f((u16)(v0 >> 16)) * w0;
    }
    a0 += c0; a1 += c1;
    float inv = 1.f / fmaxf((float)(end - beg), 1.f);
    ushort2 r; r.x = f2b(a0 * inv); r.y = f2b(a1 * inv);
    *reinterpret_cast<ushort2*>(out + (size_t)node * 128 + lane * 2) = r;
}

// ---------------- gather max (msgs >= 0, 0-init valid; both relations) ----------------
__global__ __launch_bounds__(256) void gather_max(
    const u16* __restrict__ hp0, const int* __restrict__ offs0,
    const int2* __restrict__ csr0, u16* __restrict__ o0,
    const u16* __restrict__ hp1, const int* __restrict__ offs1,
    const int2* __restrict__ csr1, u16* __restrict__ o1)
{
    int b = blockIdx.x;
    int rel = b >= 25000;
    const u16* hp = rel ? hp1 : hp0;
    const int* offs = rel ? offs1 : offs0;
    const int2* csr = rel ? csr1 : csr0;
    u16* out = rel ? o1 : o0;
    int node = (b - rel * 25000) * 4 + (threadIdx.x >> 6);
    int lane = threadIdx.x & 63;
    int beg = offs[node], end = offs[node + 1];
    float a0 = 0.f, a1 = 0.f, c0 = 0.f, c1 = 0.f;
    int e = beg;
    for (; e + 2 <= end; e += 2) {
        int2 m0 = csr[e], m1 = csr[e + 1];
        u32 v0 = *reinterpret_cast<const u32*>(hp + (size_t)m0.x * 128 + lane * 2);
        u32 v1 = *reinterpret_cast<const u32*>(hp + (size_t)m1.x * 128 + lane * 2);
        float w0 = __int_as_float(m0.y), w1 = __int_as_float(m1.y);
        a0 = fmaxf(a0, b2f((u16)(v0 & 0xFFFFu)) * w0); a1 = fmaxf(a1, b2f((u16)(v0 >> 16)) * w0);
        c0 = fmaxf(c0, b2f((u16)(v1 & 0xFFFFu)) * w1); c1 = fmaxf(c1, b2f((u16)(v1 >> 16)) * w1);
    }
    if (e < end) {
        int2 m0 = csr[e];
        u32 v0 = *reinterpret_cast<const u32*>(hp + (size_t)m0.x * 128 + lane * 2);
        float w0 = __int_as_float(m0.y);
        a0 = fmaxf(a0, b2f((u16)(v0 & 0xFFFFu)) * w0); a1 = fmaxf(a1, b2f((u16)(v0 >> 16)) * w0);
    }
    a0 = fmaxf(a0, c0); a1 = fmaxf(a1, c1);
    ushort2 r; r.x = f2b(a0); r.y = f2b(a1);
    *reinterpret_cast<ushort2*>(out + (size_t)node * 128 + lane * 2) = r;
}

// ---------------- 3-pair accumulate GEMM, B in LDS (XOR-swizzled) ----------------
// C[NN x NF*16] = act(sum_p A_p @ B_p + bias); A bf16 [NN][128], B^T bf16 [3*NF*16][128]
// 512 threads = 8 waves; each wave: one 32-row tile per loop iter. NN % 32 == 0.
template<int NF, bool RELU, bool OUTF32>
__global__ __launch_bounds__(512) void gemm3(
    const u16* __restrict__ A0, const u16* __restrict__ A1, const u16* __restrict__ A2,
    const u16* __restrict__ Bbase, const float* __restrict__ bias,
    float* __restrict__ outF, u16* __restrict__ outB)
{
    constexpr int BROWS = 3 * NF * 16;
    constexpr int NTILES = NN / 32;
    __shared__ char lds[BROWS * 256];
    for (int c = threadIdx.x; c < BROWS * 16; c += 512) {
        int n = c >> 4, kc = c & 15;
        uint4 v = *reinterpret_cast<const uint4*>(Bbase + n * 128 + kc * 8);
        int byte = (n * 256 + kc * 16) ^ ((n & 7) << 4);
        *reinterpret_cast<uint4*>(&lds[byte]) = v;
    }
    __syncthreads();

    const int w = threadIdx.x >> 6, l = threadIdx.x & 63;
    const int l15 = l & 15, lk = (l >> 4) << 3;
    const int rq = (l >> 4) << 2;
    const u16* As[3] = {A0, A1, A2};

    for (int tile = blockIdx.x * 8 + w; tile < NTILES; tile += gridDim.x * 8) {
        const size_t rowbase = (size_t)tile * 32;
        f32x4 acc[2][NF];
#pragma unroll
        for (int rf = 0; rf < 2; ++rf)
#pragma unroll
            for (int cf = 0; cf < NF; ++cf)
                acc[rf][cf] = f32x4{0.f, 0.f, 0.f, 0.f};

#pragma unroll
        for (int p = 0; p < 3; ++p) {
            const u16* A = As[p] + rowbase * 128;
            bf16x8 a0f[4], a1f[4];
#pragma unroll
            for (int ks = 0; ks < 4; ++ks) {
                int k0 = ks * 32 + lk;
                a0f[ks] = *reinterpret_cast<const bf16x8*>(A + (size_t)l15 * 128 + k0);
                a1f[ks] = *reinterpret_cast<const bf16x8*>(A + (size_t)(16 + l15) * 128 + k0);
            }
#pragma unroll
            for (int ks = 0; ks < 4; ++ks) {
#pragma unroll
                for (int cf = 0; cf < NF; ++cf) {
                    int n = p * (NF * 16) + cf * 16 + l15;
                    int byte = (n * 256 + ks * 64 + lk * 2) ^ ((n & 7) << 4);
                    bf16x8 b = *reinterpret_cast<const bf16x8*>(&lds[byte]);
                    acc[0][cf] = __builtin_amdgcn_mfma_f32_16x16x32_bf16(a0f[ks], b, acc[0][cf], 0, 0, 0);
                    acc[1][cf] = __builtin_amdgcn_mfma_f32_16x16x32_bf16(a1f[ks], b, acc[1][cf], 0, 0, 0);
                }
            }
        }

#pragma unroll
        for (int cf = 0; cf < NF; ++cf) {
            const int col = cf * 16 + l15;
            const float bv = bias[col];
#pragma unroll
            for (int rf = 0; rf < 2; ++rf) {
#pragma unroll
                for (int j = 0; j < 4; ++j) {
                    const size_t row = rowbase + rf * 16 + rq + j;
                    float v = acc[rf][cf][j] + bv;
                    if (RELU) v = fmaxf(v, 0.f);
                    if (OUTF32) outF[row * (NF * 16) + col] = v;
                    else        outB[row * (NF * 16) + col] = f2b(v);
                }
            }
        }
    }
}

// ---------------- dual-output Wp GEMM: hp0 = relu(h@Wp0+bp0), hp1 = relu(h@Wp1+bp1) ----------------
// 512 threads = 8 waves; each wave: one 16-row tile per iter (A read once for both outputs).
__global__ __launch_bounds__(512) void gemm_wp(
    const u16* __restrict__ A, const u16* __restrict__ Bbase,
    const float* __restrict__ bias0, const float* __restrict__ bias1,
    u16* __restrict__ out0, u16* __restrict__ out1)
{
    constexpr int NTILES = NN / 16;
    __shared__ char lds[2 * 128 * 256];   // 64 KB
    for (int c = threadIdx.x; c < 2 * 128 * 16; c += 512) {
        int n = c >> 4, kc = c & 15;
        uint4 v = *reinterpret_cast<const uint4*>(Bbase + n * 128 + kc * 8);
        int byte = (n * 256 + kc * 16) ^ ((n & 7) << 4);
        *reinterpret_cast<uint4*>(&lds[byte]) = v;
    }
    __syncthreads();

    const int w = threadIdx.x >> 6, l = threadIdx.x & 63;
    const int l15 = l & 15, lk = (l >> 4) << 3;
    const int rq = (l >> 4) << 2;

    for (int tile = blockIdx.x * 8 + w; tile < NTILES; tile += gridDim.x * 8) {
        const size_t rowbase = (size_t)tile * 16;
        f32x4 acc[2][8];
#pragma unroll
        for (int p = 0; p < 2; ++p)
#pragma unroll
            for (int cf = 0; cf < 8; ++cf)
                acc[p][cf] = f32x4{0.f, 0.f, 0.f, 0.f};

        bf16x8 af[4];
#pragma unroll
        for (int ks = 0; ks < 4; ++ks) {
            int k0 = ks * 32 + lk;
            af[ks] = *reinterpret_cast<const bf16x8*>(A + (rowbase + l15) * 128 + k0);
        }
#pragma unroll
        for (int p = 0; p < 2; ++p) {
#pragma unroll
            for (int ks = 0; ks < 4; ++ks) {
#pragma unroll
                for (int cf = 0; cf < 8; ++cf) {
                    int n = p * 128 + cf * 16 + l15;
                    int byte = (n * 256 + ks * 64 + lk * 2) ^ ((n & 7) << 4);
                    bf16x8 b = *reinterpret_cast<const bf16x8*>(&lds[byte]);
                    acc[p][cf] = __builtin_amdgcn_mfma_f32_16x16x32_bf16(af[ks], b, acc[p][cf], 0, 0, 0);
                }
            }
        }

#pragma unroll
        for (int cf = 0; cf < 8; ++cf) {
            const int col = cf * 16 + l15;
            const float bv0 = bias0[col], bv1 = bias1[col];
#pragma unroll
            for (int j = 0; j < 4; ++j) {
                const size_t row = rowbase + rq + j;
                out0[row * 128 + col] = f2b(fmaxf(acc[0][cf][j] + bv0, 0.f));
                out1[row * 128 + col] = f2b(fmaxf(acc[1][cf][j] + bv1, 0.f));
            }
        }
    }
}

extern "C" void kernel_launch(void* const* d_in, const int* in_sizes, int n_in,
                              void* d_out, int out_size, void* d_ws, size_t ws_size,
                              hipStream_t stream)
{
    const float* x     = (const float*)d_in[0];
    const int*   src0  = (const int*)d_in[1];
    const int*   dst0  = (const int*)d_in[2];
    const float* ew0   = (const float*)d_in[3];
    const int*   src1  = (const int*)d_in[4];
    const int*   dst1  = (const int*)d_in[5];
    const float* ew1   = (const float*)d_in[6];
    const float* Ws0_0 = (const float*)d_in[7];
    const float* Wn0_0 = (const float*)d_in[8];
    const float* b0_0  = (const float*)d_in[9];
    const float* Wp_0  = (const float*)d_in[10];
    const float* bp_0  = (const float*)d_in[11];
    const float* Ws1_0 = (const float*)d_in[12];
    const float* Wn1_0 = (const float*)d_in[13];
    const float* b1_0  = (const float*)d_in[14];
    const float* Ws0_1 = (const float*)d_in[15];
    const float* Wn0_1 = (const float*)d_in[16];
    const float* b0_1  = (const float*)d_in[17];
    const float* Wp_1  = (const float*)d_in[18];
    const float* bp_1  = (const float*)d_in[19];
    const float* Ws1_1 = (const float*)d_in[20];
    const float* Wn1_1 = (const float*)d_in[21];
    const float* b1_1  = (const float*)d_in[22];

    char* ws = (char*)d_ws;
    u16*   x16   = (u16*)(ws + 0);            // x bf16; reused as hp0 later
    u16*   h16   = (u16*)(ws + 25600000);
    u16*   a0    = (u16*)(ws + 51200000);     // mean-agg r0; reused as max-agg r0
    u16*   a1    = (u16*)(ws + 76800000);     // mean-agg r1; reused as max-agg r1
    u16*   hp1   = (u16*)(ws + 102400000);
    int2*  csr0  = (int2*)(ws + 128000000);
    int2*  csr1  = (int2*)(ws + 132800000);
    int*   offs0 = (int*)(ws + 137600000);
    int*   offs1 = (int*)(ws + 138000016);
    int*   cur0  = (int*)(ws + 138400032);
    int*   cur1  = (int*)(ws + 138800032);
    int*   deg0  = (int*)(ws + 139200032);
    int*   deg1  = (int*)(ws + 139600032);    // contiguous with deg0
    int*   bsA   = (int*)(ws + 140000032);
    int*   bsB   = (int*)(ws + 140000544);
    u16*   wts   = (u16*)(ws + 140001056);
    float* bsum0 = (float*)(ws + 140214560);
    float* bsum1 = (float*)(ws + 140215072);

    u16* hp0 = x16;                           // x16 dead after layer-0 GEMM

    prep_weights<<<417, 256, 0, stream>>>(Ws0_0, Ws0_1, Wn0_0, Wn0_1, Wp_0, Wp_1,
                                          Ws1_0, Ws1_1, Wn1_0, Wn1_1,
                                          b0_0, b0_1, b1_0, b1_1, wts, bsum0, bsum1);
    conv_x<<<12500, 256, 0, stream>>>(x, x16);

    // ---- CSR build ----
    hipMemsetAsync(deg0, 0, 800000, stream);
    deg_count<<<2344, 256, 0, stream>>>(dst0, dst1, deg0, deg1);
    scan_local<<<196, 1024, 0, stream>>>(deg0, deg1, offs0, offs1, bsA, bsB);
    scan_bsums<<<2, 128, 0, stream>>>(bsA, bsB);
    scan_add<<<784, 256, 0, stream>>>(offs0, offs1, bsA, bsB, cur0, cur1);
    build_csr<<<4688, 256, 0, stream>>>(src0, dst0, ew0, src1, dst1, ew1,
                                        cur0, cur1, csr0, csr1);

    // ---- layer 0 ----
    gather_mean<<<50000, 256, 0, stream>>>(x16, offs0, csr0, a0, offs1, csr1, a1);
    gemm3<8, true, false><<<256, 512, 0, stream>>>(
        x16, a0, a1, wts, bsum0, nullptr, h16);

    // ---- layer 1 ----
    gemm_wp<<<512, 512, 0, stream>>>(h16, wts + 49152, bp_0, bp_1, hp0, hp1);
    gather_max<<<50000, 256, 0, stream>>>(hp0, offs0, csr0, a0, hp1, offs1, csr1, a1);
    gemm3<4, false, true><<<384, 512, 0, stream>>>(
        h16, a0, a1, wts + 81920, bsum1, (float*)d_out, nullptr);
}

// Round 4
// 476.673 us; speedup vs baseline: 8.2225x; 1.0823x over previous
//
#include <hip/hip_runtime.h>

typedef short bf16x8 __attribute__((ext_vector_type(8)));
typedef float f32x4 __attribute__((ext_vector_type(4)));
typedef unsigned short u16;
typedef unsigned int u32;

#define NN 100000
#define NE 600000

__device__ __forceinline__ u16 f2b(float f) {
    u32 u = __float_as_uint(f);
    return (u16)((u + 0x7FFFu + ((u >> 16) & 1u)) >> 16);
}
__device__ __forceinline__ float b2f(u16 h) { return __uint_as_float(((u32)h) << 16); }

// ---------------- weight prep: transpose + bf16, combined sums ----------------
// wts layout (u16): 0 Wsum0T[128][128], 16384 Wn0r0T, 32768 Wn0r1T,
//   49152 Wp0T[128][128], 65536 Wp1T (contiguous 256x128 for dual GEMM),
//   81920 Wsum1T[64][128], 90112 Wn1r0T, 98304 Wn1r1T
__global__ void prep_weights(
    const float* __restrict__ Ws0_0, const float* __restrict__ Ws0_1,
    const float* __restrict__ Wn0_0, const float* __restrict__ Wn0_1,
    const float* __restrict__ Wp_0,  const float* __restrict__ Wp_1,
    const float* __restrict__ Ws1_0, const float* __restrict__ Ws1_1,
    const float* __restrict__ Wn1_0, const float* __restrict__ Wn1_1,
    const float* __restrict__ b0_0, const float* __restrict__ b0_1,
    const float* __restrict__ b1_0, const float* __restrict__ b1_1,
    const float* __restrict__ bp_0, const float* __restrict__ bp_1,
    u16* __restrict__ w, float* __restrict__ bsum0, float* __restrict__ bsum1,
    float* __restrict__ bpc)
{
    int t = blockIdx.x * 256 + threadIdx.x;
    if (t < 81920) {                      // five 128x128 transposes
        int m = t >> 14, u = t & 16383;
        int n = u >> 7, k = u & 127;      // out[n][k] = in[k][n]
        float v;
        if (m == 0)      v = Ws0_0[k * 128 + n] + Ws0_1[k * 128 + n];
        else if (m == 1) v = Wn0_0[k * 128 + n];
        else if (m == 2) v = Wn0_1[k * 128 + n];
        else if (m == 3) v = Wp_0[k * 128 + n];
        else             v = Wp_1[k * 128 + n];
        w[t] = f2b(v);
    } else if (t < 106496) {              // three 64x128 transposed (from 128x64)
        int u = t - 81920;
        int m = u >> 13; u &= 8191;
        int n = u >> 7, k = u & 127;
        float v;
        if (m == 0)      v = Ws1_0[k * 64 + n] + Ws1_1[k * 64 + n];
        else if (m == 1) v = Wn1_0[k * 64 + n];
        else             v = Wn1_1[k * 64 + n];
        w[t] = f2b(v);
    } else if (t < 106624) {
        int i = t - 106496; bsum0[i] = b0_0[i] + b0_1[i];
    } else if (t < 106688) {
        int i = t - 106624; bsum1[i] = b1_0[i] + b1_1[i];
    } else if (t < 106944) {
        int i = t - 106688; bpc[i] = (i < 128) ? bp_0[i] : bp_1[i - 128];
    }
}

// ---------------- x -> bf16 ----------------
__global__ void conv_x(const float* __restrict__ x, u16* __restrict__ o) {
    int t = blockIdx.x * 256 + threadIdx.x;           // exactly NN*128/4 threads
    const float4 v = reinterpret_cast<const float4*>(x)[t];
    ushort4 r; r.x = f2b(v.x); r.y = f2b(v.y); r.z = f2b(v.z); r.w = f2b(v.w);
    reinterpret_cast<ushort4*>(o)[t] = r;
}

// ---------------- in-degree counts for both relations ----------------
__global__ void deg_count(const int* __restrict__ d0, const int* __restrict__ d1,
                          int* __restrict__ g0, int* __restrict__ g1) {
    int e = blockIdx.x * 256 + threadIdx.x;
    if (e < NE) { atomicAdd(&g0[d0[e]], 1); atomicAdd(&g1[d1[e]], 1); }
}

// ---------------- prefix scan (both relations in one dispatch) ----------------
__global__ void scan_local(const int* __restrict__ deg0, const int* __restrict__ deg1,
                           int* __restrict__ offs0, int* __restrict__ offs1,
                           int* __restrict__ bsA, int* __restrict__ bsB)
{
    __shared__ int sm[1024];
    int rel = blockIdx.x >= 98;
    int blk = blockIdx.x - rel * 98;
    const int* in = rel ? deg1 : deg0;
    int* out = rel ? offs1 : offs0;
    int* bsum = rel ? bsB : bsA;
    int t = threadIdx.x;
    int i = blk * 1024 + t;
    int v = (i < NN) ? in[i] : 0;
    sm[t] = v;
    __syncthreads();
    for (int off = 1; off < 1024; off <<= 1) {
        int add = (t >= off) ? sm[t - off] : 0;
        __syncthreads();
        sm[t] += add;
        __syncthreads();
    }
    if (i < NN) out[i] = sm[t] - v;            // exclusive
    if (t == 1023) bsum[blk] = sm[1023];
}

__global__ void scan_bsums(int* __restrict__ bsA, int* __restrict__ bsB)
{
    __shared__ int sm[128];
    int* bsum = blockIdx.x ? bsB : bsA;
    int t = threadIdx.x;
    int v = (t < 98) ? bsum[t] : 0;
    sm[t] = v;
    __syncthreads();
    for (int off = 1; off < 128; off <<= 1) {
        int add = (t >= off) ? sm[t - off] : 0;
        __syncthreads();
        sm[t] += add;
        __syncthreads();
    }
    if (t < 98) bsum[t] = sm[t] - v;           // exclusive
}

__global__ void scan_add(int* __restrict__ offs0, int* __restrict__ offs1,
                         const int* __restrict__ bsA, const int* __restrict__ bsB,
                         int* __restrict__ cur0, int* __restrict__ cur1)
{
    int rel = blockIdx.x >= 392;
    int i = (blockIdx.x - rel * 392) * 256 + threadIdx.x;
    int* offs = rel ? offs1 : offs0;
    int* cur = rel ? cur1 : cur0;
    const int* bsum = rel ? bsB : bsA;
    if (i < NN) {
        int v = offs[i] + bsum[i >> 10];
        offs[i] = v;
        cur[i] = v;
    }
    if (i == 0) offs[NN] = NE;
}

// ---------------- CSR build (both relations) ----------------
__global__ void build_csr(const int* __restrict__ src0, const int* __restrict__ dst0,
                          const float* __restrict__ ew0,
                          const int* __restrict__ src1, const int* __restrict__ dst1,
                          const float* __restrict__ ew1,
                          int* __restrict__ cur0, int* __restrict__ cur1,
                          int2* __restrict__ csr0, int2* __restrict__ csr1)
{
    int t = blockIdx.x * 256 + threadIdx.x;
    if (t < NE) {
        int p = atomicAdd(&cur0[dst0[t]], 1);
        csr0[p] = make_int2(src0[t], __float_as_int(ew0[t]));
    } else if (t < 2 * NE) {
        int e = t - NE;
        int p = atomicAdd(&cur1[dst1[e]], 1);
        csr1[p] = make_int2(src1[e], __float_as_int(ew1[e]));
    }
}

// ---------------- gather mean (bf16 input, both relations, unroll-2) ----------------
__global__ __launch_bounds__(256) void gather_mean(
    const u16* __restrict__ x16,
    const int* __restrict__ offs0, const int2* __restrict__ csr0, u16* __restrict__ o0,
    const int* __restrict__ offs1, const int2* __restrict__ csr1, u16* __restrict__ o1)
{
    int b = blockIdx.x;
    int rel = b >= 25000;
    const int* offs = rel ? offs1 : offs0;
    const int2* csr = rel ? csr1 : csr0;
    u16* out = rel ? o1 : o0;
    int node = (b - rel * 25000) * 4 + (threadIdx.x >> 6);
    int lane = threadIdx.x & 63;
    int beg = offs[node], end = offs[node + 1];
    float a0 = 0.f, a1 = 0.f, c0 = 0.f, c1 = 0.f;
    int e = beg;
    for (; e + 2 <= end; e += 2) {
        int2 m0 = csr[e], m1 = csr[e + 1];
        u32 v0 = *reinterpret_cast<const u32*>(x16 + (size_t)m0.x * 128 + lane * 2);
        u32 v1 = *reinterpret_cast<const u32*>(x16 + (size_t)m1.x * 128 + lane * 2);
        float w0 = __int_as_float(m0.y), w1 = __int_as_float(m1.y);
        a0 += b2f((u16)(v0 & 0xFFFFu)) * w0; a1 += b2f((u16)(v0 >> 16)) * w0;
        c0 += b2f((u16)(v1 & 0xFFFFu)) * w1; c1 += b2f((u16)(v1 >> 16)) * w1;
    }
    if (e < end) {
        int2 m0 = csr[e];
        u32 v0 = *reinterpret_cast<const u32*>(x16 + (size_t)m0.x * 128 + lane * 2);
        float w0 = __int_as_float(m0.y);
        a0 += b2f((u16)(v0 & 0xFFFFu)) * w0; a1 += b2f((u16)(v0 >> 16)) * w0;
    }
    a0 += c0; a1 += c1;
    float inv = 1.f / fmaxf((float)(end - beg), 1.f);
    ushort2 r; r.x = f2b(a0 * inv); r.y = f2b(a1 * inv);
    *reinterpret_cast<ushort2*>(out + (size_t)node * 128 + lane * 2) = r;
}

// ---------------- gather max (msgs >= 0, 0-init valid; both relations) ----------------
__global__ __launch_bounds__(256) void gather_max(
    const u16* __restrict__ hp0, const int* __restrict__ offs0,
    const int2* __restrict__ csr0, u16* __restrict__ o0,
    const u16* __restrict__ hp1, const int* __restrict__ offs1,
    const int2* __restrict__ csr1, u16* __restrict__ o1)
{
    int b = blockIdx.x;
    int rel = b >= 25000;
    const u16* hp = rel ? hp1 : hp0;
    const int* offs = rel ? offs1 : offs0;
    const int2* csr = rel ? csr1 : csr0;
    u16* out = rel ? o1 : o0;
    int node = (b - rel * 25000) * 4 + (threadIdx.x >> 6);
    int lane = threadIdx.x & 63;
    int beg = offs[node], end = offs[node + 1];
    float a0 = 0.f, a1 = 0.f, c0 = 0.f, c1 = 0.f;
    int e = beg;
    for (; e + 2 <= end; e += 2) {
        int2 m0 = csr[e], m1 = csr[e + 1];
        u32 v0 = *reinterpret_cast<const u32*>(hp + (size_t)m0.x * 128 + lane * 2);
        u32 v1 = *reinterpret_cast<const u32*>(hp + (size_t)m1.x * 128 + lane * 2);
        float w0 = __int_as_float(m0.y), w1 = __int_as_float(m1.y);
        a0 = fmaxf(a0, b2f((u16)(v0 & 0xFFFFu)) * w0); a1 = fmaxf(a1, b2f((u16)(v0 >> 16)) * w0);
        c0 = fmaxf(c0, b2f((u16)(v1 & 0xFFFFu)) * w1); c1 = fmaxf(c1, b2f((u16)(v1 >> 16)) * w1);
    }
    if (e < end) {
        int2 m0 = csr[e];
        u32 v0 = *reinterpret_cast<const u32*>(hp + (size_t)m0.x * 128 + lane * 2);
        float w0 = __int_as_float(m0.y);
        a0 = fmaxf(a0, b2f((u16)(v0 & 0xFFFFu)) * w0); a1 = fmaxf(a1, b2f((u16)(v0 >> 16)) * w0);
    }
    a0 = fmaxf(a0, c0); a1 = fmaxf(a1, c1);
    ushort2 r; r.x = f2b(a0); r.y = f2b(a1);
    *reinterpret_cast<ushort2*>(out + (size_t)node * 128 + lane * 2) = r;
}

// ---------------- register-B multi-pair MFMA GEMM (no LDS, no barriers) ----------------
// C[NN x NC] = act(sum_p A_p @ B_p + bias); A bf16 [NN][128], BT bf16 [NPAIR*NC][128].
// Each wave owns a 32-col slice (colgroup) and holds its B fragments in registers;
// waves of a block share A rows -> L1 dedups. Grid-stride over 32-row tiles.
// DUAL: NPAIR=1 GEMM over concatenated [W0T;W1T] (NC=256), writing two [.][128] buffers.
template<int NPAIR, int COLGROUPS, int WAVES, bool RELU, bool OUTF32, bool DUAL>
__global__ __launch_bounds__(WAVES * 64) void gemm_reg(
    const u16* __restrict__ A0, const u16* __restrict__ A1, const u16* __restrict__ A2,
    const u16* __restrict__ BT, const float* __restrict__ bias,
    float* __restrict__ outF, u16* __restrict__ outB, u16* __restrict__ outB2)
{
    constexpr int NC = COLGROUPS * 32;
    constexpr int RT = WAVES / COLGROUPS;     // row-tiles per block iteration
    constexpr int OST = DUAL ? (NC / 2) : NC; // output row stride
    constexpr int NTILES = NN / 32;
    const int w = threadIdx.x >> 6, l = threadIdx.x & 63;
    const int cg = w % COLGROUPS, rsub = w / COLGROUPS;
    const int l15 = l & 15, lk = (l >> 4) << 3, rq = (l >> 4) << 2;

    // B fragments in registers (all compile-time indexed)
    bf16x8 bfr[NPAIR][4][2];
#pragma unroll
    for (int p = 0; p < NPAIR; ++p)
#pragma unroll
        for (int ks = 0; ks < 4; ++ks)
#pragma unroll
            for (int cf = 0; cf < 2; ++cf) {
                int n = p * NC + cg * 32 + cf * 16 + l15;
                bfr[p][ks][cf] = *reinterpret_cast<const bf16x8*>(BT + (size_t)n * 128 + ks * 32 + lk);
            }

    const u16* As[3] = {A0, A1, A2};
    const float bv0 = bias[cg * 32 + l15];
    const float bv1 = bias[cg * 32 + 16 + l15];

    for (int tile = blockIdx.x * RT + rsub; tile < NTILES; tile += gridDim.x * RT) {
        const size_t rowbase = (size_t)tile * 32;
        f32x4 acc[2][2];
#pragma unroll
        for (int rf = 0; rf < 2; ++rf)
#pragma unroll
            for (int cf = 0; cf < 2; ++cf)
                acc[rf][cf] = f32x4{0.f, 0.f, 0.f, 0.f};

#pragma unroll
        for (int p = 0; p < NPAIR; ++p) {
            const u16* A = As[p] + rowbase * 128;
#pragma unroll
            for (int ks = 0; ks < 4; ++ks) {
                const int k0 = ks * 32 + lk;
                bf16x8 a0 = *reinterpret_cast<const bf16x8*>(A + (size_t)l15 * 128 + k0);
                bf16x8 a1 = *reinterpret_cast<const bf16x8*>(A + (size_t)(16 + l15) * 128 + k0);
                acc[0][0] = __builtin_amdgcn_mfma_f32_16x16x32_bf16(a0, bfr[p][ks][0], acc[0][0], 0, 0, 0);
                acc[0][1] = __builtin_amdgcn_mfma_f32_16x16x32_bf16(a0, bfr[p][ks][1], acc[0][1], 0, 0, 0);
                acc[1][0] = __builtin_amdgcn_mfma_f32_16x16x32_bf16(a1, bfr[p][ks][0], acc[1][0], 0, 0, 0);
                acc[1][1] = __builtin_amdgcn_mfma_f32_16x16x32_bf16(a1, bfr[p][ks][1], acc[1][1], 0, 0, 0);
            }
        }

        u16* ob = outB;
        if (DUAL && cg >= 4) ob = outB2;
        const int colbase = (DUAL ? (cg & 3) : cg) * 32;
#pragma unroll
        for (int cf = 0; cf < 2; ++cf) {
            const int col = colbase + cf * 16 + l15;
            const float bv = cf ? bv1 : bv0;
#pragma unroll
            for (int rf = 0; rf < 2; ++rf) {
#pragma unroll
                for (int j = 0; j < 4; ++j) {
                    const size_t row = rowbase + rf * 16 + rq + j;
                    float v = acc[rf][cf][j] + bv;
                    if (RELU) v = fmaxf(v, 0.f);
                    if (OUTF32) outF[row * OST + col] = v;
                    else        ob[row * OST + col] = f2b(v);
                }
            }
        }
    }
}

extern "C" void kernel_launch(void* const* d_in, const int* in_sizes, int n_in,
                              void* d_out, int out_size, void* d_ws, size_t ws_size,
                              hipStream_t stream)
{
    const float* x     = (const float*)d_in[0];
    const int*   src0  = (const int*)d_in[1];
    const int*   dst0  = (const int*)d_in[2];
    const float* ew0   = (const float*)d_in[3];
    const int*   src1  = (const int*)d_in[4];
    const int*   dst1  = (const int*)d_in[5];
    const float* ew1   = (const float*)d_in[6];
    const float* Ws0_0 = (const float*)d_in[7];
    const float* Wn0_0 = (const float*)d_in[8];
    const float* b0_0  = (const float*)d_in[9];
    const float* Wp_0  = (const float*)d_in[10];
    const float* bp_0  = (const float*)d_in[11];
    const float* Ws1_0 = (const float*)d_in[12];
    const float* Wn1_0 = (const float*)d_in[13];
    const float* b1_0  = (const float*)d_in[14];
    const float* Ws0_1 = (const float*)d_in[15];
    const float* Wn0_1 = (const float*)d_in[16];
    const float* b0_1  = (const float*)d_in[17];
    const float* Wp_1  = (const float*)d_in[18];
    const float* bp_1  = (const float*)d_in[19];
    const float* Ws1_1 = (const float*)d_in[20];
    const float* Wn1_1 = (const float*)d_in[21];
    const float* b1_1  = (const float*)d_in[22];

    char* ws = (char*)d_ws;
    u16*   x16   = (u16*)(ws + 0);            // x bf16; reused as hp0 later
    u16*   h16   = (u16*)(ws + 25600000);
    u16*   a0    = (u16*)(ws + 51200000);     // mean-agg r0; reused as max-agg r0
    u16*   a1    = (u16*)(ws + 76800000);     // mean-agg r1; reused as max-agg r1
    u16*   hp1   = (u16*)(ws + 102400000);
    int2*  csr0  = (int2*)(ws + 128000000);
    int2*  csr1  = (int2*)(ws + 132800000);
    int*   offs0 = (int*)(ws + 137600000);
    int*   offs1 = (int*)(ws + 138000016);
    int*   cur0  = (int*)(ws + 138400032);
    int*   cur1  = (int*)(ws + 138800032);
    int*   deg0  = (int*)(ws + 139200032);
    int*   deg1  = (int*)(ws + 139600032);    // contiguous with deg0
    int*   bsA   = (int*)(ws + 140000032);
    int*   bsB   = (int*)(ws + 140000544);
    u16*   wts   = (u16*)(ws + 140001056);
    float* bsum0 = (float*)(ws + 140214560);
    float* bsum1 = (float*)(ws + 140215072);
    float* bpc   = (float*)(ws + 140215584);

    u16* hp0 = x16;                           // x16 dead after layer-0 GEMM

    prep_weights<<<418, 256, 0, stream>>>(Ws0_0, Ws0_1, Wn0_0, Wn0_1, Wp_0, Wp_1,
                                          Ws1_0, Ws1_1, Wn1_0, Wn1_1,
                                          b0_0, b0_1, b1_0, b1_1, bp_0, bp_1,
                                          wts, bsum0, bsum1, bpc);
    conv_x<<<12500, 256, 0, stream>>>(x, x16);

    // ---- CSR build ----
    hipMemsetAsync(deg0, 0, 800000, stream);
    deg_count<<<2344, 256, 0, stream>>>(dst0, dst1, deg0, deg1);
    scan_local<<<196, 1024, 0, stream>>>(deg0, deg1, offs0, offs1, bsA, bsB);
    scan_bsums<<<2, 128, 0, stream>>>(bsA, bsB);
    scan_add<<<784, 256, 0, stream>>>(offs0, offs1, bsA, bsB, cur0, cur1);
    build_csr<<<4688, 256, 0, stream>>>(src0, dst0, ew0, src1, dst1, ew1,
                                        cur0, cur1, csr0, csr1);

    // ---- layer 0 ----
    gather_mean<<<50000, 256, 0, stream>>>(x16, offs0, csr0, a0, offs1, csr1, a1);
    gemm_reg<3, 4, 4, true, false, false><<<1024, 256, 0, stream>>>(
        x16, a0, a1, wts, bsum0, nullptr, h16, nullptr);

    // ---- layer 1: dual Wp GEMM (N=256 over [Wp0T;Wp1T]) ----
    gemm_reg<1, 8, 8, true, false, true><<<512, 512, 0, stream>>>(
        h16, nullptr, nullptr, wts + 49152, bpc, nullptr, hp0, hp1);
    gather_max<<<50000, 256, 0, stream>>>(hp0, offs0, csr0, a0, hp1, offs1, csr1, a1);
    gemm_reg<3, 2, 4, false, true, false><<<782, 256, 0, stream>>>(
        h16, a0, a1, wts + 81920, bsum1, (float*)d_out, nullptr, nullptr);
}

// Round 5
// 400.354 us; speedup vs baseline: 9.7899x; 1.1906x over previous
//
#include <hip/hip_runtime.h>

typedef short bf16x8 __attribute__((ext_vector_type(8)));
typedef float f32x4 __attribute__((ext_vector_type(4)));
typedef unsigned short u16;
typedef unsigned int u32;

#define NN 100000
#define NE 600000

__device__ __forceinline__ u16 f2b(float f) {
    u32 u = __float_as_uint(f);
    return (u16)((u + 0x7FFFu + ((u >> 16) & 1u)) >> 16);
}

// ---------------- fused setup: x->bf16 | weight transpose+bf16 | deg count ----------------
// wts layout (u16): 0 Wsum0T[128][128], 16384 Wn0r0T, 32768 Wn0r1T,
//   49152 Wp0T[128][128], 65536 Wp1T, 81920 Wsum1T[64][128], 90112 Wn1r0T, 98304 Wn1r1T
__global__ void fused_setup(
    const float* __restrict__ x, u16* __restrict__ xo,
    const float* __restrict__ Ws0_0, const float* __restrict__ Ws0_1,
    const float* __restrict__ Wn0_0, const float* __restrict__ Wn0_1,
    const float* __restrict__ Wp_0,  const float* __restrict__ Wp_1,
    const float* __restrict__ Ws1_0, const float* __restrict__ Ws1_1,
    const float* __restrict__ Wn1_0, const float* __restrict__ Wn1_1,
    const float* __restrict__ b0_0, const float* __restrict__ b0_1,
    const float* __restrict__ b1_0, const float* __restrict__ b1_1,
    const float* __restrict__ bp_0, const float* __restrict__ bp_1,
    u16* __restrict__ w, float* __restrict__ bsum0, float* __restrict__ bsum1,
    float* __restrict__ bpc,
    const int* __restrict__ d0, const int* __restrict__ d1,
    int* __restrict__ g0, int* __restrict__ g1)
{
    int bb = blockIdx.x;
    if (bb < 12500) {                         // x -> bf16 (NN*128/4 threads)
        int t = bb * 256 + threadIdx.x;
        const float4 v = reinterpret_cast<const float4*>(x)[t];
        ushort4 r; r.x = f2b(v.x); r.y = f2b(v.y); r.z = f2b(v.z); r.w = f2b(v.w);
        reinterpret_cast<ushort4*>(xo)[t] = r;
    } else if (bb < 12918) {                  // weight prep
        int t = (bb - 12500) * 256 + threadIdx.x;
        if (t < 81920) {                      // five 128x128 transposes
            int m = t >> 14, u = t & 16383;
            int n = u >> 7, k = u & 127;
            float v;
            if (m == 0)      v = Ws0_0[k * 128 + n] + Ws0_1[k * 128 + n];
            else if (m == 1) v = Wn0_0[k * 128 + n];
            else if (m == 2) v = Wn0_1[k * 128 + n];
            else if (m == 3) v = Wp_0[k * 128 + n];
            else             v = Wp_1[k * 128 + n];
            w[t] = f2b(v);
        } else if (t < 106496) {              // three 64x128 transposed
            int u = t - 81920;
            int m = u >> 13; u &= 8191;
            int n = u >> 7, k = u & 127;
            float v;
            if (m == 0)      v = Ws1_0[k * 64 + n] + Ws1_1[k * 64 + n];
            else if (m == 1) v = Wn1_0[k * 64 + n];
            else             v = Wn1_1[k * 64 + n];
            w[t] = f2b(v);
        } else if (t < 106624) {
            int i = t - 106496; bsum0[i] = b0_0[i] + b0_1[i];
        } else if (t < 106688) {
            int i = t - 106624; bsum1[i] = b1_0[i] + b1_1[i];
        } else if (t < 106944) {
            int i = t - 106688; bpc[i] = (i < 128) ? bp_0[i] : bp_1[i - 128];
        }
    } else {                                  // in-degree counts
        int e = (bb - 12918) * 256 + threadIdx.x;
        if (e < NE) { atomicAdd(&g0[d0[e]], 1); atomicAdd(&g1[d1[e]], 1); }
    }
}

// ---------------- prefix scan ----------------
__global__ void scan_local(const int* __restrict__ deg0, const int* __restrict__ deg1,
                           int* __restrict__ offs0, int* __restrict__ offs1,
                           int* __restrict__ bsA, int* __restrict__ bsB)
{
    __shared__ int sm[1024];
    int rel = blockIdx.x >= 98;
    int blk = blockIdx.x - rel * 98;
    const int* in = rel ? deg1 : deg0;
    int* out = rel ? offs1 : offs0;
    int* bsum = rel ? bsB : bsA;
    int t = threadIdx.x;
    int i = blk * 1024 + t;
    int v = (i < NN) ? in[i] : 0;
    sm[t] = v;
    __syncthreads();
    for (int off = 1; off < 1024; off <<= 1) {
        int add = (t >= off) ? sm[t - off] : 0;
        __syncthreads();
        sm[t] += add;
        __syncthreads();
    }
    if (i < NN) out[i] = sm[t] - v;            // exclusive
    if (t == 1023) bsum[blk] = sm[1023];
}

__global__ void scan_bsums(int* __restrict__ bsA, int* __restrict__ bsB)
{
    __shared__ int sm[128];
    int* bsum = blockIdx.x ? bsB : bsA;
    int t = threadIdx.x;
    int v = (t < 98) ? bsum[t] : 0;
    sm[t] = v;
    __syncthreads();
    for (int off = 1; off < 128; off <<= 1) {
        int add = (t >= off) ? sm[t - off] : 0;
        __syncthreads();
        sm[t] += add;
        __syncthreads();
    }
    if (t < 98) bsum[t] = sm[t] - v;           // exclusive
}

__global__ void scan_add(int* __restrict__ offs0, int* __restrict__ offs1,
                         const int* __restrict__ bsA, const int* __restrict__ bsB,
                         int* __restrict__ cur0, int* __restrict__ cur1)
{
    int rel = blockIdx.x >= 392;
    int i = (blockIdx.x - rel * 392) * 256 + threadIdx.x;
    int* offs = rel ? offs1 : offs0;
    int* cur = rel ? cur1 : cur0;
    const int* bsum = rel ? bsB : bsA;
    if (i < NN) {
        int v = offs[i] + bsum[i >> 10];
        offs[i] = v;
        cur[i] = v;
    }
    if (i == 0) offs[NN] = NE;
}

// ---------------- CSR build: packed u32 entry = (src << 15) | round(ew*32767) ----------------
__global__ void build_csr(const int* __restrict__ src0, const int* __restrict__ dst0,
                          const float* __restrict__ ew0,
                          const int* __restrict__ src1, const int* __restrict__ dst1,
                          const float* __restrict__ ew1,
                          int* __restrict__ cur0, int* __restrict__ cur1,
                          u32* __restrict__ csr0, u32* __restrict__ csr1)
{
    int t = blockIdx.x * 256 + threadIdx.x;
    if (t < 4) { csr0[NE + t] = 0; csr1[NE + t] = 0; }   // pads for unroll over-read
    if (t < NE) {
        int p = atomicAdd(&cur0[dst0[t]], 1);
        u32 q = (u32)__float2int_rn(ew0[t] * 32767.f);
        csr0[p] = ((u32)src0[t] << 15) | q;
    } else if (t < 2 * NE) {
        int e = t - NE;
        int p = atomicAdd(&cur1[dst1[e]], 1);
        u32 q = (u32)__float2int_rn(ew1[e] * 32767.f);
        csr1[p] = ((u32)src1[e] << 15) | q;
    }
}

// ---------------- gather (mean or max), packed CSR, wave per node ----------------
// Lane handles 2 features. Scalar (wave-uniform) CSR walk; padded unroll-4 with
// weight-masking: over-read slots get w=0 (values are real in-array data -> finite,
// and for MAX all messages >= 0 so fmax(acc,0)=acc).
template<bool MAXAGG>
__global__ __launch_bounds__(256) void gather(
    const u16* __restrict__ F0, const u16* __restrict__ F1,
    const int* __restrict__ offs0, const u32* __restrict__ csr0, u16* __restrict__ o0,
    const int* __restrict__ offs1, const u32* __restrict__ csr1, u16* __restrict__ o1)
{
    int b = blockIdx.x;
    int rel = b >= 25000;
    const u16* F = rel ? F1 : F0;
    const int* offs = rel ? offs1 : offs0;
    const u32* csr = rel ? csr1 : csr0;
    u16* out = rel ? o1 : o0;
    int node = (b - rel * 25000) * 4 + (threadIdx.x >> 6);
    int lane = threadIdx.x & 63;
    int beg = __builtin_amdgcn_readfirstlane(offs[node]);
    int end = __builtin_amdgcn_readfirstlane(offs[node + 1]);
    const u16* base = F + (lane << 1);

    float A0 = 0.f, A1 = 0.f, B0 = 0.f, B1 = 0.f;
    float C0 = 0.f, C1 = 0.f, D0 = 0.f, D1 = 0.f;

    for (int e = beg; e < end; e += 4) {
        u32 E0 = csr[e], E1 = csr[e + 1], E2 = csr[e + 2], E3 = csr[e + 3];
        float w0 = (float)(E0 & 0x7FFFu);
        float w1 = (e + 1 < end) ? (float)(E1 & 0x7FFFu) : 0.f;
        float w2 = (e + 2 < end) ? (float)(E2 & 0x7FFFu) : 0.f;
        float w3 = (e + 3 < end) ? (float)(E3 & 0x7FFFu) : 0.f;
        u32 v0 = *reinterpret_cast<const u32*>(base + ((E0 >> 15) << 7));
        u32 v1 = *reinterpret_cast<const u32*>(base + ((E1 >> 15) << 7));
        u32 v2 = *reinterpret_cast<const u32*>(base + ((E2 >> 15) << 7));
        u32 v3 = *reinterpret_cast<const u32*>(base + ((E3 >> 15) << 7));
        if (MAXAGG) {
            A0 = fmaxf(A0, __uint_as_float(v0 << 16) * w0);
            A1 = fmaxf(A1, __uint_as_float(v0 & 0xFFFF0000u) * w0);
            B0 = fmaxf(B0, __uint_as_float(v1 << 16) * w1);
            B1 = fmaxf(B1, __uint_as_float(v1 & 0xFFFF0000u) * w1);
            C0 = fmaxf(C0, __uint_as_float(v2 << 16) * w2);
            C1 = fmaxf(C1, __uint_as_float(v2 & 0xFFFF0000u) * w2);
            D0 = fmaxf(D0, __uint_as_float(v3 << 16) * w3);
            D1 = fmaxf(D1, __uint_as_float(v3 & 0xFFFF0000u) * w3);
        } else {
            A0 = fmaf(__uint_as_float(v0 << 16), w0, A0);
            A1 = fmaf(__uint_as_float(v0 & 0xFFFF0000u), w0, A1);
            B0 = fmaf(__uint_as_float(v1 << 16), w1, B0);
            B1 = fmaf(__uint_as_float(v1 & 0xFFFF0000u), w1, B1);
            C0 = fmaf(__uint_as_float(v2 << 16), w2, C0);
            C1 = fmaf(__uint_as_float(v2 & 0xFFFF0000u), w2, C1);
            D0 = fmaf(__uint_as_float(v3 << 16), w3, D0);
            D1 = fmaf(__uint_as_float(v3 & 0xFFFF0000u), w3, D1);
        }
    }

    float a0, a1, scale;
    if (MAXAGG) {
        a0 = fmaxf(fmaxf(A0, B0), fmaxf(C0, D0));
        a1 = fmaxf(fmaxf(A1, B1), fmaxf(C1, D1));
        scale = 1.f / 32767.f;
    } else {
        a0 = (A0 + B0) + (C0 + D0);
        a1 = (A1 + B1) + (C1 + D1);
        scale = 1.f / (32767.f * fmaxf((float)(end - beg), 1.f));
    }
    ushort2 r; r.x = f2b(a0 * scale); r.y = f2b(a1 * scale);
    *reinterpret_cast<ushort2*>(out + (size_t)node * 128 + (lane << 1)) = r;
}

// ---------------- register-B multi-pair MFMA GEMM (no LDS, no barriers) ----------------
template<int NPAIR, int COLGROUPS, int WAVES, bool RELU, bool OUTF32, bool DUAL>
__global__ __launch_bounds__(WAVES * 64) void gemm_reg(
    const u16* __restrict__ A0, const u16* __restrict__ A1, const u16* __restrict__ A2,
    const u16* __restrict__ BT, const float* __restrict__ bias,
    float* __restrict__ outF, u16* __restrict__ outB, u16* __restrict__ outB2)
{
    constexpr int NC = COLGROUPS * 32;
    constexpr int RT = WAVES / COLGROUPS;
    constexpr int OST = DUAL ? (NC / 2) : NC;
    constexpr int NTILES = NN / 32;
    const int w = threadIdx.x >> 6, l = threadIdx.x & 63;
    const int cg = w % COLGROUPS, rsub = w / COLGROUPS;
    const int l15 = l & 15, lk = (l >> 4) << 3, rq = (l >> 4) << 2;

    bf16x8 bfr[NPAIR][4][2];
#pragma unroll
    for (int p = 0; p < NPAIR; ++p)
#pragma unroll
        for (int ks = 0; ks < 4; ++ks)
#pragma unroll
            for (int cf = 0; cf < 2; ++cf) {
                int n = p * NC + cg * 32 + cf * 16 + l15;
                bfr[p][ks][cf] = *reinterpret_cast<const bf16x8*>(BT + (size_t)n * 128 + ks * 32 + lk);
            }

    const u16* As[3] = {A0, A1, A2};
    const float bv0 = bias[cg * 32 + l15];
    const float bv1 = bias[cg * 32 + 16 + l15];

    for (int tile = blockIdx.x * RT + rsub; tile < NTILES; tile += gridDim.x * RT) {
        const size_t rowbase = (size_t)tile * 32;
        f32x4 acc[2][2];
#pragma unroll
        for (int rf = 0; rf < 2; ++rf)
#pragma unroll
            for (int cf = 0; cf < 2; ++cf)
                acc[rf][cf] = f32x4{0.f, 0.f, 0.f, 0.f};

#pragma unroll
        for (int p = 0; p < NPAIR; ++p) {
            const u16* A = As[p] + rowbase * 128;
#pragma unroll
            for (int ks = 0; ks < 4; ++ks) {
                const int k0 = ks * 32 + lk;
                bf16x8 a0 = *reinterpret_cast<const bf16x8*>(A + (size_t)l15 * 128 + k0);
                bf16x8 a1 = *reinterpret_cast<const bf16x8*>(A + (size_t)(16 + l15) * 128 + k0);
                acc[0][0] = __builtin_amdgcn_mfma_f32_16x16x32_bf16(a0, bfr[p][ks][0], acc[0][0], 0, 0, 0);
                acc[0][1] = __builtin_amdgcn_mfma_f32_16x16x32_bf16(a0, bfr[p][ks][1], acc[0][1], 0, 0, 0);
                acc[1][0] = __builtin_amdgcn_mfma_f32_16x16x32_bf16(a1, bfr[p][ks][0], acc[1][0], 0, 0, 0);
                acc[1][1] = __builtin_amdgcn_mfma_f32_16x16x32_bf16(a1, bfr[p][ks][1], acc[1][1], 0, 0, 0);
            }
        }

        u16* ob = outB;
        if (DUAL && cg >= 4) ob = outB2;
        const int colbase = (DUAL ? (cg & 3) : cg) * 32;
#pragma unroll
        for (int cf = 0; cf < 2; ++cf) {
            const int col = colbase + cf * 16 + l15;
            const float bv = cf ? bv1 : bv0;
#pragma unroll
            for (int rf = 0; rf < 2; ++rf) {
#pragma unroll
                for (int j = 0; j < 4; ++j) {
                    const size_t row = rowbase + rf * 16 + rq + j;
                    float v = acc[rf][cf][j] + bv;
                    if (RELU) v = fmaxf(v, 0.f);
                    if (OUTF32) outF[row * OST + col] = v;
                    else        ob[row * OST + col] = f2b(v);
                }
            }
        }
    }
}

extern "C" void kernel_launch(void* const* d_in, const int* in_sizes, int n_in,
                              void* d_out, int out_size, void* d_ws, size_t ws_size,
                              hipStream_t stream)
{
    const float* x     = (const float*)d_in[0];
    const int*   src0  = (const int*)d_in[1];
    const int*   dst0  = (const int*)d_in[2];
    const float* ew0   = (const float*)d_in[3];
    const int*   src1  = (const int*)d_in[4];
    const int*   dst1  = (const int*)d_in[5];
    const float* ew1   = (const float*)d_in[6];
    const float* Ws0_0 = (const float*)d_in[7];
    const float* Wn0_0 = (const float*)d_in[8];
    const float* b0_0  = (const float*)d_in[9];
    const float* Wp_0  = (const float*)d_in[10];
    const float* bp_0  = (const float*)d_in[11];
    const float* Ws1_0 = (const float*)d_in[12];
    const float* Wn1_0 = (const float*)d_in[13];
    const float* b1_0  = (const float*)d_in[14];
    const float* Ws0_1 = (const float*)d_in[15];
    const float* Wn0_1 = (const float*)d_in[16];
    const float* b0_1  = (const float*)d_in[17];
    const float* Wp_1  = (const float*)d_in[18];
    const float* bp_1  = (const float*)d_in[19];
    const float* Ws1_1 = (const float*)d_in[20];
    const float* Wn1_1 = (const float*)d_in[21];
    const float* b1_1  = (const float*)d_in[22];

    char* ws = (char*)d_ws;
    u16*   x16   = (u16*)(ws + 0);            // x bf16; reused as hp0 later
    u16*   h16   = (u16*)(ws + 25600000);
    u16*   a0    = (u16*)(ws + 51200000);     // mean-agg r0; reused as max-agg r0
    u16*   a1    = (u16*)(ws + 76800000);     // mean-agg r1; reused as max-agg r1
    u16*   hp1   = (u16*)(ws + 102400000);
    u32*   csr0  = (u32*)(ws + 128000000);    // NE+4 packed entries
    u32*   csr1  = (u32*)(ws + 130400016);
    int*   offs0 = (int*)(ws + 132800032);
    int*   offs1 = (int*)(ws + 133200048);
    int*   cur0  = (int*)(ws + 133600064);
    int*   cur1  = (int*)(ws + 134000064);
    int*   deg0  = (int*)(ws + 134400064);
    int*   deg1  = (int*)(ws + 134800064);    // contiguous with deg0
    int*   bsA   = (int*)(ws + 135200064);
    int*   bsB   = (int*)(ws + 135200576);
    u16*   wts   = (u16*)(ws + 135201088);
    float* bsum0 = (float*)(ws + 135414080);
    float* bsum1 = (float*)(ws + 135414592);
    float* bpc   = (float*)(ws + 135415104);

    u16* hp0 = x16;                           // x16 dead after layer-0 GEMM

    hipMemsetAsync(deg0, 0, 800000, stream);
    fused_setup<<<15262, 256, 0, stream>>>(
        x, x16, Ws0_0, Ws0_1, Wn0_0, Wn0_1, Wp_0, Wp_1,
        Ws1_0, Ws1_1, Wn1_0, Wn1_1, b0_0, b0_1, b1_0, b1_1, bp_0, bp_1,
        wts, bsum0, bsum1, bpc, dst0, dst1, deg0, deg1);

    scan_local<<<196, 1024, 0, stream>>>(deg0, deg1, offs0, offs1, bsA, bsB);
    scan_bsums<<<2, 128, 0, stream>>>(bsA, bsB);
    scan_add<<<784, 256, 0, stream>>>(offs0, offs1, bsA, bsB, cur0, cur1);
    build_csr<<<4688, 256, 0, stream>>>(src0, dst0, ew0, src1, dst1, ew1,
                                        cur0, cur1, csr0, csr1);

    // ---- layer 0 ----
    gather<false><<<50000, 256, 0, stream>>>(x16, x16, offs0, csr0, a0, offs1, csr1, a1);
    gemm_reg<3, 4, 4, true, false, false><<<1024, 256, 0, stream>>>(
        x16, a0, a1, wts, bsum0, nullptr, h16, nullptr);

    // ---- layer 1 ----
    gemm_reg<1, 8, 8, true, false, true><<<512, 512, 0, stream>>>(
        h16, nullptr, nullptr, wts + 49152, bpc, nullptr, hp0, hp1);
    gather<true><<<50000, 256, 0, stream>>>(hp0, hp1, offs0, csr0, a0, offs1, csr1, a1);
    gemm_reg<3, 2, 4, false, true, false><<<782, 256, 0, stream>>>(
        h16, a0, a1, wts + 81920, bsum1, (float*)d_out, nullptr, nullptr);
}

// Round 6
// 377.511 us; speedup vs baseline: 10.3823x; 1.0605x over previous
//
#include <hip/hip_runtime.h>

typedef short bf16x8 __attribute__((ext_vector_type(8)));
typedef float f32x4 __attribute__((ext_vector_type(4)));
typedef unsigned short u16;
typedef unsigned int u32;

#define NN 100000
#define NE 600000
#define CSR_CHUNKS 300
#define EPC 2000          // NE / CSR_CHUNKS
#define PART 12500        // NN / 8

__device__ __forceinline__ u16 f2b(float f) {
    u32 u = __float_as_uint(f);
    return (u16)((u + 0x7FFFu + ((u >> 16) & 1u)) >> 16);
}

// ---------------- fused setup: x->bf16 | weight transpose+bf16 | deg count ----------------
// wts layout (u16): 0 Wsum0T[128][128], 16384 Wn0r0T, 32768 Wn0r1T,
//   49152 Wp0T[128][128], 65536 Wp1T, 81920 Wsum1T[64][128], 90112 Wn1r0T, 98304 Wn1r1T
__global__ void fused_setup(
    const float* __restrict__ x, u16* __restrict__ xo,
    const float* __restrict__ Ws0_0, const float* __restrict__ Ws0_1,
    const float* __restrict__ Wn0_0, const float* __restrict__ Wn0_1,
    const float* __restrict__ Wp_0,  const float* __restrict__ Wp_1,
    const float* __restrict__ Ws1_0, const float* __restrict__ Ws1_1,
    const float* __restrict__ Wn1_0, const float* __restrict__ Wn1_1,
    const float* __restrict__ b0_0, const float* __restrict__ b0_1,
    const float* __restrict__ b1_0, const float* __restrict__ b1_1,
    const float* __restrict__ bp_0, const float* __restrict__ bp_1,
    u16* __restrict__ w, float* __restrict__ bsum0, float* __restrict__ bsum1,
    float* __restrict__ bpc,
    const int* __restrict__ d0, const int* __restrict__ d1,
    int* __restrict__ g0, int* __restrict__ g1)
{
    int bb = blockIdx.x;
    if (bb < 12500) {                         // x -> bf16 (NN*128/4 threads)
        int t = bb * 256 + threadIdx.x;
        const float4 v = reinterpret_cast<const float4*>(x)[t];
        ushort4 r; r.x = f2b(v.x); r.y = f2b(v.y); r.z = f2b(v.z); r.w = f2b(v.w);
        reinterpret_cast<ushort4*>(xo)[t] = r;
    } else if (bb < 12918) {                  // weight prep
        int t = (bb - 12500) * 256 + threadIdx.x;
        if (t < 81920) {                      // five 128x128 transposes
            int m = t >> 14, u = t & 16383;
            int n = u >> 7, k = u & 127;
            float v;
            if (m == 0)      v = Ws0_0[k * 128 + n] + Ws0_1[k * 128 + n];
            else if (m == 1) v = Wn0_0[k * 128 + n];
            else if (m == 2) v = Wn0_1[k * 128 + n];
            else if (m == 3) v = Wp_0[k * 128 + n];
            else             v = Wp_1[k * 128 + n];
            w[t] = f2b(v);
        } else if (t < 106496) {              // three 64x128 transposed
            int u = t - 81920;
            int m = u >> 13; u &= 8191;
            int n = u >> 7, k = u & 127;
            float v;
            if (m == 0)      v = Ws1_0[k * 64 + n] + Ws1_1[k * 64 + n];
            else if (m == 1) v = Wn1_0[k * 64 + n];
            else             v = Wn1_1[k * 64 + n];
            w[t] = f2b(v);
        } else if (t < 106624) {
            int i = t - 106496; bsum0[i] = b0_0[i] + b0_1[i];
        } else if (t < 106688) {
            int i = t - 106624; bsum1[i] = b1_0[i] + b1_1[i];
        } else if (t < 106944) {
            int i = t - 106688; bpc[i] = (i < 128) ? bp_0[i] : bp_1[i - 128];
        }
    } else {                                  // in-degree counts
        int e = (bb - 12918) * 256 + threadIdx.x;
        if (e < NE) { atomicAdd(&g0[d0[e]], 1); atomicAdd(&g1[d1[e]], 1); }
    }
}

// ---------------- prefix scan ----------------
__global__ void scan_local(const int* __restrict__ deg0, const int* __restrict__ deg1,
                           int* __restrict__ offs0, int* __restrict__ offs1,
                           int* __restrict__ bsA, int* __restrict__ bsB)
{
    __shared__ int sm[1024];
    int rel = blockIdx.x >= 98;
    int blk = blockIdx.x - rel * 98;
    const int* in = rel ? deg1 : deg0;
    int* out = rel ? offs1 : offs0;
    int* bsum = rel ? bsB : bsA;
    int t = threadIdx.x;
    int i = blk * 1024 + t;
    int v = (i < NN) ? in[i] : 0;
    sm[t] = v;
    __syncthreads();
    for (int off = 1; off < 1024; off <<= 1) {
        int add = (t >= off) ? sm[t - off] : 0;
        __syncthreads();
        sm[t] += add;
        __syncthreads();
    }
    if (i < NN) out[i] = sm[t] - v;            // exclusive
    if (t == 1023) bsum[blk] = sm[1023];
}

__global__ void scan_bsums(int* __restrict__ bsA, int* __restrict__ bsB)
{
    __shared__ int sm[128];
    int* bsum = blockIdx.x ? bsB : bsA;
    int t = threadIdx.x;
    int v = (t < 98) ? bsum[t] : 0;
    sm[t] = v;
    __syncthreads();
    for (int off = 1; off < 128; off <<= 1) {
        int add = (t >= off) ? sm[t - off] : 0;
        __syncthreads();
        sm[t] += add;
        __syncthreads();
    }
    if (t < 98) bsum[t] = sm[t] - v;           // exclusive
}

__global__ void scan_add(int* __restrict__ offs0, int* __restrict__ offs1,
                         const int* __restrict__ bsA, const int* __restrict__ bsB,
                         int* __restrict__ cur0, int* __restrict__ cur1,
                         u32* __restrict__ csr0, u32* __restrict__ csr1)
{
    int rel = blockIdx.x >= 392;
    int i = (blockIdx.x - rel * 392) * 256 + threadIdx.x;
    int* offs = rel ? offs1 : offs0;
    int* cur = rel ? cur1 : cur0;
    const int* bsum = rel ? bsB : bsA;
    if (i < NN) {
        int v = offs[i] + bsum[i >> 10];
        offs[i] = v;
        cur[i] = v;
    }
    if (i == 0) offs[NN] = NE;
    if (blockIdx.x == 0 && threadIdx.x < 4) {  // pads for gather unroll over-read
        csr0[NE + threadIdx.x] = 0;
        csr1[NE + threadIdx.x] = 0;
    }
}

// ---------------- CSR build, XCD-partitioned by dst range ----------------
// grid = 2 * 8 * CSR_CHUNKS. Blocks with (bb & 7) == g handle dst in [g*PART,(g+1)*PART)
// and round-robin onto XCD g -> every csr line is written by exactly one XCD's L2
// (kills the cross-XCD partial-line writeback amplification seen in rounds 4-5).
__global__ __launch_bounds__(256) void build_csr_part(
    const int* __restrict__ src0, const int* __restrict__ dst0,
    const float* __restrict__ ew0,
    const int* __restrict__ src1, const int* __restrict__ dst1,
    const float* __restrict__ ew1,
    int* __restrict__ cur0, int* __restrict__ cur1,
    u32* __restrict__ csr0, u32* __restrict__ csr1)
{
    int b = blockIdx.x;
    int rel = b >= 8 * CSR_CHUNKS;
    int bb = b - rel * 8 * CSR_CHUNKS;
    int part = bb & 7, chunk = bb >> 3;
    const int lo = part * PART, hi = lo + PART;
    const int* src = rel ? src1 : src0;
    const int* dst = rel ? dst1 : dst0;
    const float* ew = rel ? ew1 : ew0;
    int* cur = rel ? cur1 : cur0;
    u32* csr = rel ? csr1 : csr0;
    const int e_end = chunk * EPC + EPC;
    for (int e = chunk * EPC + threadIdx.x; e < e_end; e += 256) {
        int d = dst[e];
        if (d >= lo && d < hi) {
            int p = atomicAdd(&cur[d], 1);
            u32 q = (u32)__float2int_rn(ew[e] * 32767.f);
            csr[p] = ((u32)src[e] << 15) | q;
        }
    }
}

// ---------------- gather (mean or max), packed CSR, wave per node ----------------
template<bool MAXAGG>
__global__ __launch_bounds__(256) void gather(
    const u16* __restrict__ F0, const u16* __restrict__ F1,
    const int* __restrict__ offs0, const u32* __restrict__ csr0, u16* __restrict__ o0,
    const int* __restrict__ offs1, const u32* __restrict__ csr1, u16* __restrict__ o1)
{
    int b = blockIdx.x;
    int rel = b >= 25000;
    const u16* F = rel ? F1 : F0;
    const int* offs = rel ? offs1 : offs0;
    const u32* csr = rel ? csr1 : csr0;
    u16* out = rel ? o1 : o0;
    int node = (b - rel * 25000) * 4 + (threadIdx.x >> 6);
    int lane = threadIdx.x & 63;
    int beg = __builtin_amdgcn_readfirstlane(offs[node]);
    int end = __builtin_amdgcn_readfirstlane(offs[node + 1]);
    const u16* base = F + (lane << 1);

    float A0 = 0.f, A1 = 0.f, B0 = 0.f, B1 = 0.f;
    float C0 = 0.f, C1 = 0.f, D0 = 0.f, D1 = 0.f;

    for (int e = beg; e < end; e += 4) {
        u32 E0 = csr[e], E1 = csr[e + 1], E2 = csr[e + 2], E3 = csr[e + 3];
        float w0 = (float)(E0 & 0x7FFFu);
        float w1 = (e + 1 < end) ? (float)(E1 & 0x7FFFu) : 0.f;
        float w2 = (e + 2 < end) ? (float)(E2 & 0x7FFFu) : 0.f;
        float w3 = (e + 3 < end) ? (float)(E3 & 0x7FFFu) : 0.f;
        u32 v0 = *reinterpret_cast<const u32*>(base + ((E0 >> 15) << 7));
        u32 v1 = *reinterpret_cast<const u32*>(base + ((E1 >> 15) << 7));
        u32 v2 = *reinterpret_cast<const u32*>(base + ((E2 >> 15) << 7));
        u32 v3 = *reinterpret_cast<const u32*>(base + ((E3 >> 15) << 7));
        if (MAXAGG) {
            A0 = fmaxf(A0, __uint_as_float(v0 << 16) * w0);
            A1 = fmaxf(A1, __uint_as_float(v0 & 0xFFFF0000u) * w0);
            B0 = fmaxf(B0, __uint_as_float(v1 << 16) * w1);
            B1 = fmaxf(B1, __uint_as_float(v1 & 0xFFFF0000u) * w1);
            C0 = fmaxf(C0, __uint_as_float(v2 << 16) * w2);
            C1 = fmaxf(C1, __uint_as_float(v2 & 0xFFFF0000u) * w2);
            D0 = fmaxf(D0, __uint_as_float(v3 << 16) * w3);
            D1 = fmaxf(D1, __uint_as_float(v3 & 0xFFFF0000u) * w3);
        } else {
            A0 = fmaf(__uint_as_float(v0 << 16), w0, A0);
            A1 = fmaf(__uint_as_float(v0 & 0xFFFF0000u), w0, A1);
            B0 = fmaf(__uint_as_float(v1 << 16), w1, B0);
            B1 = fmaf(__uint_as_float(v1 & 0xFFFF0000u), w1, B1);
            C0 = fmaf(__uint_as_float(v2 << 16), w2, C0);
            C1 = fmaf(__uint_as_float(v2 & 0xFFFF0000u), w2, C1);
            D0 = fmaf(__uint_as_float(v3 << 16), w3, D0);
            D1 = fmaf(__uint_as_float(v3 & 0xFFFF0000u), w3, D1);
        }
    }

    float a0, a1, scale;
    if (MAXAGG) {
        a0 = fmaxf(fmaxf(A0, B0), fmaxf(C0, D0));
        a1 = fmaxf(fmaxf(A1, B1), fmaxf(C1, D1));
        scale = 1.f / 32767.f;
    } else {
        a0 = (A0 + B0) + (C0 + D0);
        a1 = (A1 + B1) + (C1 + D1);
        scale = 1.f / (32767.f * fmaxf((float)(end - beg), 1.f));
    }
    ushort2 r; r.x = f2b(a0 * scale); r.y = f2b(a1 * scale);
    *reinterpret_cast<ushort2*>(out + (size_t)node * 128 + (lane << 1)) = r;
}

// ---------------- register-B multi-pair MFMA GEMM (no LDS, no barriers) ----------------
template<int NPAIR, int COLGROUPS, int WAVES, bool RELU, bool OUTF32, bool DUAL>
__global__ __launch_bounds__(WAVES * 64) void gemm_reg(
    const u16* __restrict__ A0, const u16* __restrict__ A1, const u16* __restrict__ A2,
    const u16* __restrict__ BT, const float* __restrict__ bias,
    float* __restrict__ outF, u16* __restrict__ outB, u16* __restrict__ outB2)
{
    constexpr int NC = COLGROUPS * 32;
    constexpr int RT = WAVES / COLGROUPS;
    constexpr int OST = DUAL ? (NC / 2) : NC;
    constexpr int NTILES = NN / 32;
    const int w = threadIdx.x >> 6, l = threadIdx.x & 63;
    const int cg = w % COLGROUPS, rsub = w / COLGROUPS;
    const int l15 = l & 15, lk = (l >> 4) << 3, rq = (l >> 4) << 2;

    bf16x8 bfr[NPAIR][4][2];
#pragma unroll
    for (int p = 0; p < NPAIR; ++p)
#pragma unroll
        for (int ks = 0; ks < 4; ++ks)
#pragma unroll
            for (int cf = 0; cf < 2; ++cf) {
                int n = p * NC + cg * 32 + cf * 16 + l15;
                bfr[p][ks][cf] = *reinterpret_cast<const bf16x8*>(BT + (size_t)n * 128 + ks * 32 + lk);
            }

    const u16* As[3] = {A0, A1, A2};
    const float bv0 = bias[cg * 32 + l15];
    const float bv1 = bias[cg * 32 + 16 + l15];

    for (int tile = blockIdx.x * RT + rsub; tile < NTILES; tile += gridDim.x * RT) {
        const size_t rowbase = (size_t)tile * 32;
        f32x4 acc[2][2];
#pragma unroll
        for (int rf = 0; rf < 2; ++rf)
#pragma unroll
            for (int cf = 0; cf < 2; ++cf)
                acc[rf][cf] = f32x4{0.f, 0.f, 0.f, 0.f};

#pragma unroll
        for (int p = 0; p < NPAIR; ++p) {
            const u16* A = As[p] + rowbase * 128;
#pragma unroll
            for (int ks = 0; ks < 4; ++ks) {
                const int k0 = ks * 32 + lk;
                bf16x8 a0 = *reinterpret_cast<const bf16x8*>(A + (size_t)l15 * 128 + k0);
                bf16x8 a1 = *reinterpret_cast<const bf16x8*>(A + (size_t)(16 + l15) * 128 + k0);
                acc[0][0] = __builtin_amdgcn_mfma_f32_16x16x32_bf16(a0, bfr[p][ks][0], acc[0][0], 0, 0, 0);
                acc[0][1] = __builtin_amdgcn_mfma_f32_16x16x32_bf16(a0, bfr[p][ks][1], acc[0][1], 0, 0, 0);
                acc[1][0] = __builtin_amdgcn_mfma_f32_16x16x32_bf16(a1, bfr[p][ks][0], acc[1][0], 0, 0, 0);
                acc[1][1] = __builtin_amdgcn_mfma_f32_16x16x32_bf16(a1, bfr[p][ks][1], acc[1][1], 0, 0, 0);
            }
        }

        u16* ob = outB;
        if (DUAL && cg >= 4) ob = outB2;
        const int colbase = (DUAL ? (cg & 3) : cg) * 32;
#pragma unroll
        for (int cf = 0; cf < 2; ++cf) {
            const int col = colbase + cf * 16 + l15;
            const float bv = cf ? bv1 : bv0;
#pragma unroll
            for (int rf = 0; rf < 2; ++rf) {
#pragma unroll
                for (int j = 0; j < 4; ++j) {
                    const size_t row = rowbase + rf * 16 + rq + j;
                    float v = acc[rf][cf][j] + bv;
                    if (RELU) v = fmaxf(v, 0.f);
                    if (OUTF32) outF[row * OST + col] = v;
                    else        ob[row * OST + col] = f2b(v);
                }
            }
        }
    }
}

extern "C" void kernel_launch(void* const* d_in, const int* in_sizes, int n_in,
                              void* d_out, int out_size, void* d_ws, size_t ws_size,
                              hipStream_t stream)
{
    const float* x     = (const float*)d_in[0];
    const int*   src0  = (const int*)d_in[1];
    const int*   dst0  = (const int*)d_in[2];
    const float* ew0   = (const float*)d_in[3];
    const int*   src1  = (const int*)d_in[4];
    const int*   dst1  = (const int*)d_in[5];
    const float* ew1   = (const float*)d_in[6];
    const float* Ws0_0 = (const float*)d_in[7];
    const float* Wn0_0 = (const float*)d_in[8];
    const float* b0_0  = (const float*)d_in[9];
    const float* Wp_0  = (const float*)d_in[10];
    const float* bp_0  = (const float*)d_in[11];
    const float* Ws1_0 = (const float*)d_in[12];
    const float* Wn1_0 = (const float*)d_in[13];
    const float* b1_0  = (const float*)d_in[14];
    const float* Ws0_1 = (const float*)d_in[15];
    const float* Wn0_1 = (const float*)d_in[16];
    const float* b0_1  = (const float*)d_in[17];
    const float* Wp_1  = (const float*)d_in[18];
    const float* bp_1  = (const float*)d_in[19];
    const float* Ws1_1 = (const float*)d_in[20];
    const float* Wn1_1 = (const float*)d_in[21];
    const float* b1_1  = (const float*)d_in[22];

    char* ws = (char*)d_ws;
    u16*   x16   = (u16*)(ws + 0);            // x bf16; reused as hp0 later
    u16*   h16   = (u16*)(ws + 25600000);
    u16*   a0    = (u16*)(ws + 51200000);     // mean-agg r0; reused as max-agg r0
    u16*   a1    = (u16*)(ws + 76800000);     // mean-agg r1; reused as max-agg r1
    u16*   hp1   = (u16*)(ws + 102400000);
    u32*   csr0  = (u32*)(ws + 128000000);    // NE+4 packed entries
    u32*   csr1  = (u32*)(ws + 130400016);
    int*   offs0 = (int*)(ws + 132800032);
    int*   offs1 = (int*)(ws + 133200048);
    int*   cur0  = (int*)(ws + 133600064);
    int*   cur1  = (int*)(ws + 134000064);
    int*   deg0  = (int*)(ws + 134400064);
    int*   deg1  = (int*)(ws + 134800064);    // contiguous with deg0
    int*   bsA   = (int*)(ws + 135200064);
    int*   bsB   = (int*)(ws + 135200576);
    u16*   wts   = (u16*)(ws + 135201088);
    float* bsum0 = (float*)(ws + 135414080);
    float* bsum1 = (float*)(ws + 135414592);
    float* bpc   = (float*)(ws + 135415104);

    u16* hp0 = x16;                           // x16 dead after layer-0 GEMM

    hipMemsetAsync(deg0, 0, 800000, stream);
    fused_setup<<<15262, 256, 0, stream>>>(
        x, x16, Ws0_0, Ws0_1, Wn0_0, Wn0_1, Wp_0, Wp_1,
        Ws1_0, Ws1_1, Wn1_0, Wn1_1, b0_0, b0_1, b1_0, b1_1, bp_0, bp_1,
        wts, bsum0, bsum1, bpc, dst0, dst1, deg0, deg1);

    scan_local<<<196, 1024, 0, stream>>>(deg0, deg1, offs0, offs1, bsA, bsB);
    scan_bsums<<<2, 128, 0, stream>>>(bsA, bsB);
    scan_add<<<784, 256, 0, stream>>>(offs0, offs1, bsA, bsB, cur0, cur1, csr0, csr1);
    build_csr_part<<<2 * 8 * CSR_CHUNKS, 256, 0, stream>>>(
        src0, dst0, ew0, src1, dst1, ew1, cur0, cur1, csr0, csr1);

    // ---- layer 0 ----
    gather<false><<<50000, 256, 0, stream>>>(x16, x16, offs0, csr0, a0, offs1, csr1, a1);
    gemm_reg<3, 4, 4, true, false, false><<<1024, 256, 0, stream>>>(
        x16, a0, a1, wts, bsum0, nullptr, h16, nullptr);

    // ---- layer 1 ----
    gemm_reg<1, 8, 8, true, false, true><<<512, 512, 0, stream>>>(
        h16, nullptr, nullptr, wts + 49152, bpc, nullptr, hp0, hp1);
    gather<true><<<50000, 256, 0, stream>>>(hp0, hp1, offs0, csr0, a0, offs1, csr1, a1);
    gemm_reg<3, 2, 4, false, true, false><<<782, 256, 0, stream>>>(
        h16, a0, a1, wts + 81920, bsum1, (float*)d_out, nullptr, nullptr);
}